// Round 6
// baseline (339.291 us; speedup 1.0000x reference)
//
#include <hip/hip_runtime.h>
#include <stdint.h>

// Problem constants (reference: B=2, S=2048, D=1024, H=16, DK=64)
#define B_  2
#define S_  2048
#define D_  1024
#define H_  16
#define DK_ 64
#define PERHEAD (S_ * DK_)  // 131072 elems per (b,h)

// exp(x*0.125) = exp2(x * 0.125*log2(e))
#define EXP2SCALE 0.18033688011112042f

typedef __attribute__((ext_vector_type(8))) short short8;   // 8 bf16 = 4 VGPRs (MFMA A/B frag)
typedef __attribute__((ext_vector_type(4))) short bf16x4;   // 4 bf16 = 2 VGPRs (16x16x16 frag)
typedef __attribute__((ext_vector_type(4))) float floatx4;  // MFMA C/D frag

#define MFMA16(a, b, c) __builtin_amdgcn_mfma_f32_16x16x32_bf16((a), (b), (c), 0, 0, 0)

// K=16 bf16 MFMA (legacy shape, present on gfx950; builtin name varies by ROCm)
#if __has_builtin(__builtin_amdgcn_mfma_f32_16x16x16bf16_1k)
#define MFMA16X16(a, b, c) __builtin_amdgcn_mfma_f32_16x16x16bf16_1k((a), (b), (c), 0, 0, 0)
#elif __has_builtin(__builtin_amdgcn_mfma_f32_16x16x16_bf16)
#define MFMA16X16(a, b, c) __builtin_amdgcn_mfma_f32_16x16x16_bf16((a), (b), (c), 0, 0, 0)
#else
static __device__ __forceinline__ floatx4 mfma16x16_asm(bf16x4 a, bf16x4 b, floatx4 c) {
  asm volatile("v_mfma_f32_16x16x16_bf16 %0, %1, %2, %0" : "+v"(c) : "v"(a), "v"(b));
  return c;
}
#define MFMA16X16(a, b, c) mfma16x16_asm((a), (b), (c))
#endif

// async global->LDS, 16B per lane (used only in the projection GEMMs)
__device__ __forceinline__ void gload_lds16(const void* g, void* lds) {
  __builtin_amdgcn_global_load_lds(
      (__attribute__((address_space(1))) void*)(void*)g,
      (__attribute__((address_space(3))) void*)lds, 16, 0, 0);
}

__device__ __forceinline__ unsigned short f2bf(float f) {
  union { float f; unsigned int u; } v;
  v.f = f;
  unsigned int r = v.u + 0x7fffu + ((v.u >> 16) & 1u);
  return (unsigned short)(r >> 16);
}

// pack two positive f32 into two bf16 (round-half-up: +0x8000 then take hi16 via v_perm)
__device__ __forceinline__ unsigned int pack_bf16_rhu(float e0, float e1) {
  unsigned int u0 = __float_as_uint(e0) + 0x8000u;
  unsigned int u1 = __float_as_uint(e1) + 0x8000u;
  return __builtin_amdgcn_perm(u1, u0, 0x07060302);  // {lo16: bf16(e0), hi16: bf16(e1)}
}

// ---------------- batched casts fp32 -> bf16 (one launch for 3 inputs / 4 weights) ----
__global__ void cast3_f32_bf16(const float* __restrict__ a0, const float* __restrict__ a1,
                               const float* __restrict__ a2,
                               unsigned short* __restrict__ o0, unsigned short* __restrict__ o1,
                               unsigned short* __restrict__ o2, int n4) {
  const float* in = (blockIdx.z == 0) ? a0 : (blockIdx.z == 1) ? a1 : a2;
  unsigned short* out = (blockIdx.z == 0) ? o0 : (blockIdx.z == 1) ? o1 : o2;
  int i = blockIdx.x * 256 + threadIdx.x;
  if (i < n4) {
    float4 f = ((const float4*)in)[i];
    uint2 p;
    p.x = (unsigned int)f2bf(f.x) | ((unsigned int)f2bf(f.y) << 16);
    p.y = (unsigned int)f2bf(f.z) | ((unsigned int)f2bf(f.w) << 16);
    ((uint2*)out)[i] = p;
  }
}
__global__ void cast4_f32_bf16(const float* __restrict__ a0, const float* __restrict__ a1,
                               const float* __restrict__ a2, const float* __restrict__ a3,
                               unsigned short* __restrict__ o0, unsigned short* __restrict__ o1,
                               unsigned short* __restrict__ o2, unsigned short* __restrict__ o3,
                               int n4) {
  const float* in = (blockIdx.z == 0) ? a0 : (blockIdx.z == 1) ? a1 : (blockIdx.z == 2) ? a2 : a3;
  unsigned short* out = (blockIdx.z == 0) ? o0 : (blockIdx.z == 1) ? o1 : (blockIdx.z == 2) ? o2 : o3;
  int i = blockIdx.x * 256 + threadIdx.x;
  if (i < n4) {
    float4 f = ((const float4*)in)[i];
    uint2 p;
    p.x = (unsigned int)f2bf(f.x) | ((unsigned int)f2bf(f.y) << 16);
    p.y = (unsigned int)f2bf(f.z) | ((unsigned int)f2bf(f.w) << 16);
    ((uint2*)out)[i] = p;
  }
}

// Fragment-ordered layouts (16x16x32 MFMA operand fragments; one frag = 16 rows x
// 32 k x bf16 = 512 elems = 64 lane-ordered 16B chunks; chunk L = row(L&15),
// k = (L>>4)*8..+7). Reader: ds/global _b128 at base + lane*16 -> conflict-free.
//
// Qf/Kf per (b,h): frag(sblk = s>>4, ks = dk>>5):  idx = sblk*2 + ks
// Vf    per (b,h): frag(kblk = key>>5, db = dk>>4): idx = kblk*4 + db  (rows = dk)

// ---------------- shared GEMM core: 128x128 tile, BK=32, 4 waves each 64x64 ----------
__device__ __forceinline__ void gemm_core(const unsigned short* __restrict__ A,
                                          const unsigned short* __restrict__ Bw,
                                          unsigned short* lA, unsigned short* lB,
                                          int m0, int n0, int tid, int lane, int wave,
                                          floatx4 acc[4][4]) {
  const int wm = (wave >> 1) * 64;
  const int wn = (wave & 1) * 64;
  for (int k0 = 0; k0 < D_; k0 += 32) {
#pragma unroll
    for (int l = 0; l < 2; ++l) {
      int c = l * 256 + tid;
      int row = c >> 2, cb = (c & 3) * 16;
      const char* ga = (const char*)A + ((size_t)(m0 + row) * D_ + k0) * 2 + cb;
      gload_lds16(ga, (char*)lA + (size_t)(l * 256 + wave * 64) * 16);
      const char* gb = (const char*)Bw + ((size_t)(n0 + row) * D_ + k0) * 2 + cb;
      gload_lds16(gb, (char*)lB + (size_t)(l * 256 + wave * 64) * 16);
    }
    __syncthreads();
    short8 af[4], bf_[4];
#pragma unroll
    for (int mt = 0; mt < 4; ++mt)
      af[mt] = *(const short8*)&lA[(wm + mt * 16 + (lane & 15)) * 32 + (lane >> 4) * 8];
#pragma unroll
    for (int nt = 0; nt < 4; ++nt)
      bf_[nt] = *(const short8*)&lB[(wn + nt * 16 + (lane & 15)) * 32 + (lane >> 4) * 8];
#pragma unroll
    for (int mt = 0; mt < 4; ++mt)
#pragma unroll
      for (int nt = 0; nt < 4; ++nt)
        acc[mt][nt] = MFMA16(af[mt], bf_[nt], acc[mt][nt]);
    __syncthreads();
  }
}

// ---------------- fused QKV projection: z selects (A, W, Out, epilogue) ----------------
__launch_bounds__(256, 2)
__global__ void gemm_qkv(const unsigned short* __restrict__ qi, const unsigned short* __restrict__ ki,
                         const unsigned short* __restrict__ vi,
                         const unsigned short* __restrict__ Wq, const unsigned short* __restrict__ Wk,
                         const unsigned short* __restrict__ Wv,
                         unsigned short* __restrict__ Qf, unsigned short* __restrict__ Kf,
                         unsigned short* __restrict__ Vf) {
  __shared__ unsigned short lA[128 * 32];
  __shared__ unsigned short lB[128 * 32];
  const int z = blockIdx.z;
  const unsigned short* A  = (z == 0) ? qi : (z == 1) ? ki : vi;
  const unsigned short* Bw = (z == 0) ? Wq : (z == 1) ? Wk : Wv;
  unsigned short* O        = (z == 0) ? Qf : (z == 1) ? Kf : Vf;
  const int tid = threadIdx.x, lane = tid & 63, wave = tid >> 6;
  const int m0 = blockIdx.y * 128, n0 = blockIdx.x * 128;
  const int wm = (wave >> 1) * 64, wn = (wave & 1) * 64;

  floatx4 acc[4][4] = {};
  gemm_core(A, Bw, lA, lB, m0, n0, tid, lane, wave, acc);

  if (z < 2) {  // Qf/Kf fragment layout
#pragma unroll
    for (int mt = 0; mt < 4; ++mt)
#pragma unroll
      for (int nt = 0; nt < 4; ++nt)
#pragma unroll
        for (int r = 0; r < 4; ++r) {
          int row = m0 + wm + mt * 16 + (lane >> 4) * 4 + r;  // token
          int col = n0 + wn + nt * 16 + (lane & 15);          // e
          int b = row >> 11, s = row & (S_ - 1);
          int h = col >> 6,  dk = col & 63;
          size_t base = (size_t)(b * H_ + h) * PERHEAD;
          int frag = (s >> 4) * 2 + (dk >> 5);
          int lp = (s & 15) | (((dk >> 3) & 3) << 4);
          O[base + (size_t)frag * 512 + lp * 8 + (dk & 7)] = f2bf(acc[mt][nt][r]);
        }
  } else {  // Vf fragment layout (rows = dk, k = key)
#pragma unroll
    for (int mt = 0; mt < 4; ++mt)
#pragma unroll
      for (int nt = 0; nt < 4; ++nt) {
        int row0 = m0 + wm + mt * 16 + (lane >> 4) * 4;  // 4 consecutive keys
        int col  = n0 + wn + nt * 16 + (lane & 15);
        int b = row0 >> 11, key0 = row0 & (S_ - 1);
        int h = col >> 6,   dk = col & 63;
        size_t base = (size_t)(b * H_ + h) * PERHEAD;
        int frag = (key0 >> 5) * 4 + (dk >> 4);
        int lp = (dk & 15) | (((key0 >> 3) & 3) << 4);
        unsigned long long pk =
            (unsigned long long)f2bf(acc[mt][nt][0]) |
            ((unsigned long long)f2bf(acc[mt][nt][1]) << 16) |
            ((unsigned long long)f2bf(acc[mt][nt][2]) << 32) |
            ((unsigned long long)f2bf(acc[mt][nt][3]) << 48);
        *(unsigned long long*)&O[base + (size_t)frag * 512 + lp * 8 + (key0 & 7)] = pk;
      }
  }
}

// ---------------- output projection: fp32 row-major ----------------
__launch_bounds__(256, 2)
__global__ void gemm_out(const unsigned short* __restrict__ A, const unsigned short* __restrict__ Bw,
                         float* __restrict__ O) {
  __shared__ unsigned short lA[128 * 32];
  __shared__ unsigned short lB[128 * 32];
  const int tid = threadIdx.x, lane = tid & 63, wave = tid >> 6;
  const int m0 = blockIdx.y * 128, n0 = blockIdx.x * 128;
  const int wm = (wave >> 1) * 64, wn = (wave & 1) * 64;
  floatx4 acc[4][4] = {};
  gemm_core(A, Bw, lA, lB, m0, n0, tid, lane, wave, acc);
#pragma unroll
  for (int mt = 0; mt < 4; ++mt)
#pragma unroll
    for (int nt = 0; nt < 4; ++nt)
#pragma unroll
      for (int r = 0; r < 4; ++r) {
        int row = m0 + wm + mt * 16 + (lane >> 4) * 4 + r;
        int col = n0 + wn + nt * 16 + (lane & 15);
        O[(size_t)row * D_ + col] = acc[mt][nt][r];
      }
}

// ---------------- Pass 1: Zl[b,q,k] = fp16( log2( sum_h exp2(s*C) ) ) ----------------
// 128x128 tiles (grid 16x16x2). No LDS, no barriers. Wave w owns q rows [q0+w*32).
__launch_bounds__(256, 3)
__global__ void compute_z(const unsigned short* __restrict__ Qf,
                          const unsigned short* __restrict__ Kf,
                          unsigned short* __restrict__ Zl) {
  const int tid = threadIdx.x, lane = tid & 63, wave = tid >> 6;
  const int k0 = blockIdx.x * 128, q0 = blockIdx.y * 128, b = blockIdx.z;

  floatx4 zacc[2][8] = {};
  const short8* qbase = (const short8*)Qf + (size_t)b * H_ * (PERHEAD / 8)
                        + ((q0 >> 4) + wave * 2) * 128 + lane;
  const short8* kbase = (const short8*)Kf + (size_t)b * H_ * (PERHEAD / 8)
                        + (k0 >> 4) * 128 + lane;

#pragma unroll 1
  for (int h = 0; h < H_; ++h) {
    short8 qf0 = qbase[0], qf1 = qbase[64];    // sq=0, ks=0/1
    short8 qf2 = qbase[128], qf3 = qbase[192]; // sq=1, ks=0/1
#pragma unroll
    for (int hf = 0; hf < 2; ++hf) {
      short8 kst[4][2];
#pragma unroll
      for (int kb = 0; kb < 4; ++kb) {
        kst[kb][0] = kbase[(hf * 4 + kb) * 128];
        kst[kb][1] = kbase[(hf * 4 + kb) * 128 + 64];
      }
#pragma unroll
      for (int kb = 0; kb < 4; ++kb) {
        floatx4 s0 = {}, s1 = {};
        s0 = MFMA16(qf0, kst[kb][0], s0);
        s0 = MFMA16(qf1, kst[kb][1], s0);
        s1 = MFMA16(qf2, kst[kb][0], s1);
        s1 = MFMA16(qf3, kst[kb][1], s1);
#pragma unroll
        for (int r = 0; r < 4; ++r) {
          zacc[0][hf * 4 + kb][r] += exp2f(s0[r] * EXP2SCALE);
          zacc[1][hf * 4 + kb][r] += exp2f(s1[r] * EXP2SCALE);
        }
      }
    }
    qbase += PERHEAD / 8;
    kbase += PERHEAD / 8;
  }

#pragma unroll
  for (int sq = 0; sq < 2; ++sq)
#pragma unroll
    for (int kb = 0; kb < 8; ++kb)
#pragma unroll
      for (int r = 0; r < 4; ++r) {
        int q = q0 + wave * 32 + sq * 16 + (lane >> 4) * 4 + r;
        int k = k0 + kb * 16 + (lane & 15);
        union { _Float16 h; unsigned short u; } cv;
        cv.h = (_Float16)log2f(zacc[sq][kb][r]);
        Zl[((size_t)b * S_ + q) * S_ + k] = cv.u;
      }
}

// ---------------- Pass 2: x^T = exp2(s*C - Lz) @ V ----------------
// Round-6 (= round-5 with the short4 name collision fixed -> bf16x4):
// BARRIER-FREE main loop. Key identity: C/D layout of sacc=mfma(K,Q)
// (key=(lane>>4)*4+r, q=lane&15) EQUALS the B-operand layout of
// v_mfma_f32_16x16x16_bf16 (k=(lane>>4)*4+j, col=lane&15). So with each wave
// owning a 16-key slice end-to-end, pack(exp(sacc)) IS the PV B-frag in-register:
// no LDS P tile, no per-iteration barriers (r0-r4 evidence: the serial
// QK->exp->LDS->barrier->PV chain was the floor; occupancy/pipelining tweaks all
// failed to beat 88.8 us). Each wave accumulates a k-partial of x^T over ALL
// 64 dk (A-operand = V frags, dk rows x wave's 16 keys); one 4-way LDS reduction
// at kernel end (2 barriers total) replaces 32 in-loop barriers.
// Head partition preserved (f mod 8 = h mod 8 -> 2 MB K/V per XCD, L2-resident).
__launch_bounds__(256, 4)
__global__ void attn_pv(const unsigned short* __restrict__ Qf,
                        const unsigned short* __restrict__ Kf,
                        const unsigned short* __restrict__ Vf,
                        const unsigned short* __restrict__ Zl,
                        unsigned short* __restrict__ X) {
  __shared__ float lX[4][32][68];  // 4 wave-partials, q x dk (dk padded 64->68)
  const int tid = threadIdx.x, lane = tid & 63, wave = tid >> 6;
  const int h = blockIdx.x, b = blockIdx.z;
  const int q0 = blockIdx.y * 32;

  const size_t headu = (size_t)(b * H_ + h) * PERHEAD;      // ushort units
  const size_t headf = headu / 8;                           // short8 units

  // Q fragments (q-tile 32: qb=0,1), layout identical to r0
  short8 qf[2][2];
#pragma unroll
  for (int qb = 0; qb < 2; ++qb) {
    const short8* qp = (const short8*)Qf + headf + ((q0 >> 4) + qb) * 128 + lane;
    qf[qb][0] = qp[0];
    qf[qb][1] = qp[64];
  }

  // K: wave w owns keys w*16 + t*64 (A-frag rows); same walk as r0
  const short8* kp = (const short8*)Kf + headf + wave * 128 + lane;  // += 512/iter

  // V as 16x16x16 A-operand: lane L needs dk = dkb*16 + (L&15),
  // keys = w*16 + t*64 + (L>>4)*4 + j (j=0..3, consecutive in Vf elem dim).
  // Vf addr = head + (kblk*4+dkb)*512 + ((dk&15)|(grp<<4))*8 + (key&7), where
  // kblk = t*2 + (w>>1), grp = (w&1)*2 + ((L>>4)>>1), elem base = ((L>>4)&1)*4.
  const int vgrp = ((wave & 1) << 1) | ((lane >> 4) >> 1);
  const unsigned short* vp = Vf + headu + (size_t)(wave >> 1) * 2048
                           + (((lane & 15) | (vgrp << 4)) << 3) + (((lane >> 4) & 1) << 2);
  // += 4096/iter (2 kblks); + dkb*512 per dk-block

  // Zl: lane L needs q = q0 + qb*16 + (L&15), k = wave*16 + t*64 + (L>>4)*4 + r
  const unsigned short* zp = Zl + ((size_t)b * S_ + q0 + (lane & 15)) * S_
                             + wave * 16 + ((lane >> 4) << 2);

  floatx4 xacc[4][2] = {};  // [dkb][qb]: k-partial of x^T[dk][q]

  // prologue: iteration-0 operands
  short8 ck0 = kp[0], ck1 = kp[64];
  uint2 va0 = *(const uint2*)(vp);
  uint2 va1 = *(const uint2*)(vp + 512);
  uint2 va2 = *(const uint2*)(vp + 1024);
  uint2 va3 = *(const uint2*)(vp + 1536);
  uint2 cz0 = *(const uint2*)(zp);
  uint2 cz1 = *(const uint2*)(zp + (size_t)16 * S_);
  kp += 512; vp += 4096; zp += 64;

#pragma unroll 2
  for (int kt = 0; kt < S_ / 64; ++kt) {
    // prefetch next iteration (named registers; guarded on last iter)
    short8 nk0, nk1;
    uint2 nv0, nv1, nv2, nv3, nz0, nz1;
    if (kt != S_ / 64 - 1) {
      nk0 = kp[0]; nk1 = kp[64];
      nv0 = *(const uint2*)(vp);
      nv1 = *(const uint2*)(vp + 512);
      nv2 = *(const uint2*)(vp + 1024);
      nv3 = *(const uint2*)(vp + 1536);
      nz0 = *(const uint2*)(zp);
      nz1 = *(const uint2*)(zp + (size_t)16 * S_);
      kp += 512; vp += 4096; zp += 64;
    }

    // S^T: m = wave's 16 keys, n = 32 q
    floatx4 sacc[2] = {};
    __builtin_amdgcn_s_setprio(1);
#pragma unroll
    for (int qb = 0; qb < 2; ++qb) {
      sacc[qb] = MFMA16(ck0, qf[qb][0], sacc[qb]);
      sacc[qb] = MFMA16(ck1, qf[qb][1], sacc[qb]);
    }
    __builtin_amdgcn_s_setprio(0);

    // P = exp2(s*C - Lz) -> bf16 B-frags, fully in-register
    bf16x4 pb[2];
#pragma unroll
    for (int qb = 0; qb < 2; ++qb) {
      uint2 zz = (qb == 0) ? cz0 : cz1;
      union { uint2 v; _Float16 hv[4]; } zu; zu.v = zz;
      float e0 = exp2f(fmaf(sacc[qb][0], EXP2SCALE, -(float)zu.hv[0]));
      float e1 = exp2f(fmaf(sacc[qb][1], EXP2SCALE, -(float)zu.hv[1]));
      float e2 = exp2f(fmaf(sacc[qb][2], EXP2SCALE, -(float)zu.hv[2]));
      float e3 = exp2f(fmaf(sacc[qb][3], EXP2SCALE, -(float)zu.hv[3]));
      union { uint2 u; bf16x4 s; } pk;
      pk.u.x = pack_bf16_rhu(e0, e1);
      pk.u.y = pack_bf16_rhu(e2, e3);
      pb[qb] = pk.s;
    }

    // PV: xacc[dkb][qb] += V^T[dk][wave's 16 keys] @ P[16 keys][q]
    __builtin_amdgcn_s_setprio(1);
#pragma unroll
    for (int dkb = 0; dkb < 4; ++dkb) {
      uint2 vv = (dkb == 0) ? va0 : (dkb == 1) ? va1 : (dkb == 2) ? va2 : va3;
      union { uint2 u; bf16x4 s; } vc; vc.u = vv;
#pragma unroll
      for (int qb = 0; qb < 2; ++qb)
        xacc[dkb][qb] = MFMA16X16(vc.s, pb[qb], xacc[dkb][qb]);
    }
    __builtin_amdgcn_s_setprio(0);

    // rotate prefetched -> current (renames under unroll)
    ck0 = nk0; ck1 = nk1;
    va0 = nv0; va1 = nv1; va2 = nv2; va3 = nv3;
    cz0 = nz0; cz1 = nz1;
  }

  // epilogue: 4-way cross-wave k-partial reduction via LDS, then coalesced stores
#pragma unroll
  for (int dkb = 0; dkb < 4; ++dkb)
#pragma unroll
    for (int qb = 0; qb < 2; ++qb)
#pragma unroll
      for (int r = 0; r < 4; ++r)
        lX[wave][qb * 16 + (lane & 15)][dkb * 16 + (lane >> 4) * 4 + r] = xacc[dkb][qb][r];
  __syncthreads();
  {
    int q = tid >> 3, c8 = (tid & 7) * 8;  // 32 rows x 8 chunks of 8
    short8 v;
#pragma unroll
    for (int j = 0; j < 8; ++j) {
      float s = lX[0][q][c8 + j] + lX[1][q][c8 + j] + lX[2][q][c8 + j] + lX[3][q][c8 + j];
      v[j] = (short)f2bf(s);
    }
    unsigned short* o = X + (size_t)(b * S_ + q0 + q) * D_ + h * DK_ + c8;
    *(short8*)&o[0] = v;
  }
}

// ---------------- launch ----------------
extern "C" void kernel_launch(void* const* d_in, const int* in_sizes, int n_in,
                              void* d_out, int out_size, void* d_ws, size_t ws_size,
                              hipStream_t stream) {
  const float* qi = (const float*)d_in[0];
  const float* ki = (const float*)d_in[1];
  const float* vi = (const float*)d_in[2];
  // d_in[3] = mask: reference discards masked_fill result -> unused
  const float* Wq = (const float*)d_in[4];
  const float* Wk = (const float*)d_in[5];
  const float* Wv = (const float*)d_in[6];
  const float* Wo = (const float*)d_in[7];

  const size_t NT = (size_t)B_ * S_ * D_;  // 4,194,304
  const size_t NW = (size_t)D_ * D_;       // 1,048,576

  unsigned short* w = (unsigned short*)d_ws;
  unsigned short* qi_bf = w; w += NT;
  unsigned short* ki_bf = w; w += NT;
  unsigned short* vi_bf = w; w += NT;
  unsigned short* Wq_bf = w; w += NW;
  unsigned short* Wk_bf = w; w += NW;
  unsigned short* Wv_bf = w; w += NW;
  unsigned short* Wo_bf = w; w += NW;
  unsigned short* Qf = w; w += NT;  // fragment-ordered per (b,h)
  unsigned short* Kf = w; w += NT;
  unsigned short* Vf = w; w += NT;
  unsigned short* Xb = w; w += NT;  // [b,s,e] row-major bf16
  unsigned short* Zl = w;           // [b,q,k] fp16 log2(Z), 16 MiB

  {
    int n4 = (int)(NT / 4);   // 1048576 -> 4096 blocks
    cast3_f32_bf16<<<dim3((n4 + 255) / 256, 1, 3), 256, 0, stream>>>(
        qi, ki, vi, qi_bf, ki_bf, vi_bf, n4);
    int n4w = (int)(NW / 4);  // 262144 -> 1024 blocks
    cast4_f32_bf16<<<dim3((n4w + 255) / 256, 1, 4), 256, 0, stream>>>(
        Wq, Wk, Wv, Wo, Wq_bf, Wk_bf, Wv_bf, Wo_bf, n4w);
  }

  gemm_qkv<<<dim3(D_ / 128, (B_ * S_) / 128, 3), 256, 0, stream>>>(
      qi_bf, ki_bf, vi_bf, Wq_bf, Wk_bf, Wv_bf, Qf, Kf, Vf);

  compute_z<<<dim3(S_ / 128, S_ / 128, B_), 256, 0, stream>>>(Qf, Kf, Zl);
  attn_pv<<<dim3(H_, S_ / 32, B_), 256, 0, stream>>>(Qf, Kf, Vf, Zl, Xb);

  gemm_out<<<dim3(D_ / 128, (B_ * S_) / 128), 256, 0, stream>>>(Xb, Wo_bf, (float*)d_out);
}

// Round 7
// 313.184 us; speedup vs baseline: 1.0834x; 1.0834x over previous
//
#include <hip/hip_runtime.h>
#include <stdint.h>

// Problem constants (reference: B=2, S=2048, D=1024, H=16, DK=64)
#define B_  2
#define S_  2048
#define D_  1024
#define H_  16
#define DK_ 64
#define PERHEAD (S_ * DK_)  // 131072 elems per (b,h)

// exp(x*0.125) = exp2(x * 0.125*log2(e))
#define EXP2SCALE 0.18033688011112042f

typedef __attribute__((ext_vector_type(8))) short short8;   // 8 bf16 = 4 VGPRs (MFMA A/B frag)
typedef __attribute__((ext_vector_type(4))) float floatx4;  // MFMA C/D frag

#define MFMA16(a, b, c) __builtin_amdgcn_mfma_f32_16x16x32_bf16((a), (b), (c), 0, 0, 0)

// async global->LDS, 16B per lane (used only in the projection GEMMs)
__device__ __forceinline__ void gload_lds16(const void* g, void* lds) {
  __builtin_amdgcn_global_load_lds(
      (__attribute__((address_space(1))) void*)(void*)g,
      (__attribute__((address_space(3))) void*)lds, 16, 0, 0);
}

__device__ __forceinline__ unsigned short f2bf(float f) {
  union { float f; unsigned int u; } v;
  v.f = f;
  unsigned int r = v.u + 0x7fffu + ((v.u >> 16) & 1u);
  return (unsigned short)(r >> 16);
}

// pack two positive f32 into two bf16 (round-half-up: +0x8000 then take hi16 via v_perm)
__device__ __forceinline__ unsigned int pack_bf16_rhu(float e0, float e1) {
  unsigned int u0 = __float_as_uint(e0) + 0x8000u;
  unsigned int u1 = __float_as_uint(e1) + 0x8000u;
  return __builtin_amdgcn_perm(u1, u0, 0x07060302);  // {u1.hi16, u0.hi16}
}

// ---------------- batched casts fp32 -> bf16 (one launch for 3 inputs / 4 weights) ----
__global__ void cast3_f32_bf16(const float* __restrict__ a0, const float* __restrict__ a1,
                               const float* __restrict__ a2,
                               unsigned short* __restrict__ o0, unsigned short* __restrict__ o1,
                               unsigned short* __restrict__ o2, int n4) {
  const float* in = (blockIdx.z == 0) ? a0 : (blockIdx.z == 1) ? a1 : a2;
  unsigned short* out = (blockIdx.z == 0) ? o0 : (blockIdx.z == 1) ? o1 : o2;
  int i = blockIdx.x * 256 + threadIdx.x;
  if (i < n4) {
    float4 f = ((const float4*)in)[i];
    uint2 p;
    p.x = (unsigned int)f2bf(f.x) | ((unsigned int)f2bf(f.y) << 16);
    p.y = (unsigned int)f2bf(f.z) | ((unsigned int)f2bf(f.w) << 16);
    ((uint2*)out)[i] = p;
  }
}
__global__ void cast4_f32_bf16(const float* __restrict__ a0, const float* __restrict__ a1,
                               const float* __restrict__ a2, const float* __restrict__ a3,
                               unsigned short* __restrict__ o0, unsigned short* __restrict__ o1,
                               unsigned short* __restrict__ o2, unsigned short* __restrict__ o3,
                               int n4) {
  const float* in = (blockIdx.z == 0) ? a0 : (blockIdx.z == 1) ? a1 : (blockIdx.z == 2) ? a2 : a3;
  unsigned short* out = (blockIdx.z == 0) ? o0 : (blockIdx.z == 1) ? o1 : (blockIdx.z == 2) ? o2 : o3;
  int i = blockIdx.x * 256 + threadIdx.x;
  if (i < n4) {
    float4 f = ((const float4*)in)[i];
    uint2 p;
    p.x = (unsigned int)f2bf(f.x) | ((unsigned int)f2bf(f.y) << 16);
    p.y = (unsigned int)f2bf(f.z) | ((unsigned int)f2bf(f.w) << 16);
    ((uint2*)out)[i] = p;
  }
}

// Fragment-ordered layouts (16x16x32 MFMA operand fragments; one frag = 16 rows x
// 32 k x bf16 = 512 elems = 64 lane-ordered 16B chunks; chunk L = row(L&15),
// k = (L>>4)*8..+7). Reader: ds/global _b128 at base + lane*16 -> conflict-free.
//
// Qf/Kf per (b,h): frag(sblk = s>>4, ks = dk>>5):  idx = sblk*2 + ks
// Vf    per (b,h): frag(kblk = key>>5, db = dk>>4): idx = kblk*4 + db  (rows = dk)

// ---------------- shared GEMM core: 128x128 tile, BK=32, 4 waves each 64x64 ----------
__device__ __forceinline__ void gemm_core(const unsigned short* __restrict__ A,
                                          const unsigned short* __restrict__ Bw,
                                          unsigned short* lA, unsigned short* lB,
                                          int m0, int n0, int tid, int lane, int wave,
                                          floatx4 acc[4][4]) {
  const int wm = (wave >> 1) * 64;
  const int wn = (wave & 1) * 64;
  for (int k0 = 0; k0 < D_; k0 += 32) {
#pragma unroll
    for (int l = 0; l < 2; ++l) {
      int c = l * 256 + tid;
      int row = c >> 2, cb = (c & 3) * 16;
      const char* ga = (const char*)A + ((size_t)(m0 + row) * D_ + k0) * 2 + cb;
      gload_lds16(ga, (char*)lA + (size_t)(l * 256 + wave * 64) * 16);
      const char* gb = (const char*)Bw + ((size_t)(n0 + row) * D_ + k0) * 2 + cb;
      gload_lds16(gb, (char*)lB + (size_t)(l * 256 + wave * 64) * 16);
    }
    __syncthreads();
    short8 af[4], bf_[4];
#pragma unroll
    for (int mt = 0; mt < 4; ++mt)
      af[mt] = *(const short8*)&lA[(wm + mt * 16 + (lane & 15)) * 32 + (lane >> 4) * 8];
#pragma unroll
    for (int nt = 0; nt < 4; ++nt)
      bf_[nt] = *(const short8*)&lB[(wn + nt * 16 + (lane & 15)) * 32 + (lane >> 4) * 8];
#pragma unroll
    for (int mt = 0; mt < 4; ++mt)
#pragma unroll
      for (int nt = 0; nt < 4; ++nt)
        acc[mt][nt] = MFMA16(af[mt], bf_[nt], acc[mt][nt]);
    __syncthreads();
  }
}

// ---------------- fused QKV projection: z selects (A, W, Out, epilogue) ----------------
__launch_bounds__(256, 2)
__global__ void gemm_qkv(const unsigned short* __restrict__ qi, const unsigned short* __restrict__ ki,
                         const unsigned short* __restrict__ vi,
                         const unsigned short* __restrict__ Wq, const unsigned short* __restrict__ Wk,
                         const unsigned short* __restrict__ Wv,
                         unsigned short* __restrict__ Qf, unsigned short* __restrict__ Kf,
                         unsigned short* __restrict__ Vf) {
  __shared__ unsigned short lA[128 * 32];
  __shared__ unsigned short lB[128 * 32];
  const int z = blockIdx.z;
  const unsigned short* A  = (z == 0) ? qi : (z == 1) ? ki : vi;
  const unsigned short* Bw = (z == 0) ? Wq : (z == 1) ? Wk : Wv;
  unsigned short* O        = (z == 0) ? Qf : (z == 1) ? Kf : Vf;
  const int tid = threadIdx.x, lane = tid & 63, wave = tid >> 6;
  const int m0 = blockIdx.y * 128, n0 = blockIdx.x * 128;
  const int wm = (wave >> 1) * 64, wn = (wave & 1) * 64;

  floatx4 acc[4][4] = {};
  gemm_core(A, Bw, lA, lB, m0, n0, tid, lane, wave, acc);

  if (z < 2) {  // Qf/Kf fragment layout
#pragma unroll
    for (int mt = 0; mt < 4; ++mt)
#pragma unroll
      for (int nt = 0; nt < 4; ++nt)
#pragma unroll
        for (int r = 0; r < 4; ++r) {
          int row = m0 + wm + mt * 16 + (lane >> 4) * 4 + r;  // token
          int col = n0 + wn + nt * 16 + (lane & 15);          // e
          int b = row >> 11, s = row & (S_ - 1);
          int h = col >> 6,  dk = col & 63;
          size_t base = (size_t)(b * H_ + h) * PERHEAD;
          int frag = (s >> 4) * 2 + (dk >> 5);
          int lp = (s & 15) | (((dk >> 3) & 3) << 4);
          O[base + (size_t)frag * 512 + lp * 8 + (dk & 7)] = f2bf(acc[mt][nt][r]);
        }
  } else {  // Vf fragment layout (rows = dk, k = key)
#pragma unroll
    for (int mt = 0; mt < 4; ++mt)
#pragma unroll
      for (int nt = 0; nt < 4; ++nt) {
        int row0 = m0 + wm + mt * 16 + (lane >> 4) * 4;  // 4 consecutive keys
        int col  = n0 + wn + nt * 16 + (lane & 15);
        int b = row0 >> 11, key0 = row0 & (S_ - 1);
        int h = col >> 6,   dk = col & 63;
        size_t base = (size_t)(b * H_ + h) * PERHEAD;
        int frag = (key0 >> 5) * 4 + (dk >> 4);
        int lp = (dk & 15) | (((key0 >> 3) & 3) << 4);
        unsigned long long pk =
            (unsigned long long)f2bf(acc[mt][nt][0]) |
            ((unsigned long long)f2bf(acc[mt][nt][1]) << 16) |
            ((unsigned long long)f2bf(acc[mt][nt][2]) << 32) |
            ((unsigned long long)f2bf(acc[mt][nt][3]) << 48);
        *(unsigned long long*)&O[base + (size_t)frag * 512 + lp * 8 + (key0 & 7)] = pk;
      }
  }
}

// ---------------- output projection: fp32 row-major ----------------
__launch_bounds__(256, 2)
__global__ void gemm_out(const unsigned short* __restrict__ A, const unsigned short* __restrict__ Bw,
                         float* __restrict__ O) {
  __shared__ unsigned short lA[128 * 32];
  __shared__ unsigned short lB[128 * 32];
  const int tid = threadIdx.x, lane = tid & 63, wave = tid >> 6;
  const int m0 = blockIdx.y * 128, n0 = blockIdx.x * 128;
  const int wm = (wave >> 1) * 64, wn = (wave & 1) * 64;
  floatx4 acc[4][4] = {};
  gemm_core(A, Bw, lA, lB, m0, n0, tid, lane, wave, acc);
#pragma unroll
  for (int mt = 0; mt < 4; ++mt)
#pragma unroll
    for (int nt = 0; nt < 4; ++nt)
#pragma unroll
      for (int r = 0; r < 4; ++r) {
        int row = m0 + wm + mt * 16 + (lane >> 4) * 4 + r;
        int col = n0 + wn + nt * 16 + (lane & 15);
        O[(size_t)row * D_ + col] = acc[mt][nt][r];
      }
}

// ---------------- Pass 1: Zl[b,q,k] = fp16( log2( sum_h exp2(s*C) ) ) ----------------
// 128x128 tiles (grid 16x16x2). No LDS, no barriers. Wave w owns q rows [q0+w*32).
__launch_bounds__(256, 3)
__global__ void compute_z(const unsigned short* __restrict__ Qf,
                          const unsigned short* __restrict__ Kf,
                          unsigned short* __restrict__ Zl) {
  const int tid = threadIdx.x, lane = tid & 63, wave = tid >> 6;
  const int k0 = blockIdx.x * 128, q0 = blockIdx.y * 128, b = blockIdx.z;

  floatx4 zacc[2][8] = {};
  const short8* qbase = (const short8*)Qf + (size_t)b * H_ * (PERHEAD / 8)
                        + ((q0 >> 4) + wave * 2) * 128 + lane;
  const short8* kbase = (const short8*)Kf + (size_t)b * H_ * (PERHEAD / 8)
                        + (k0 >> 4) * 128 + lane;

#pragma unroll 1
  for (int h = 0; h < H_; ++h) {
    short8 qf0 = qbase[0], qf1 = qbase[64];    // sq=0, ks=0/1
    short8 qf2 = qbase[128], qf3 = qbase[192]; // sq=1, ks=0/1
#pragma unroll
    for (int hf = 0; hf < 2; ++hf) {
      short8 kst[4][2];
#pragma unroll
      for (int kb = 0; kb < 4; ++kb) {
        kst[kb][0] = kbase[(hf * 4 + kb) * 128];
        kst[kb][1] = kbase[(hf * 4 + kb) * 128 + 64];
      }
#pragma unroll
      for (int kb = 0; kb < 4; ++kb) {
        floatx4 s0 = {}, s1 = {};
        s0 = MFMA16(qf0, kst[kb][0], s0);
        s0 = MFMA16(qf1, kst[kb][1], s0);
        s1 = MFMA16(qf2, kst[kb][0], s1);
        s1 = MFMA16(qf3, kst[kb][1], s1);
#pragma unroll
        for (int r = 0; r < 4; ++r) {
          zacc[0][hf * 4 + kb][r] += exp2f(s0[r] * EXP2SCALE);
          zacc[1][hf * 4 + kb][r] += exp2f(s1[r] * EXP2SCALE);
        }
      }
    }
    qbase += PERHEAD / 8;
    kbase += PERHEAD / 8;
  }

#pragma unroll
  for (int sq = 0; sq < 2; ++sq)
#pragma unroll
    for (int kb = 0; kb < 8; ++kb)
#pragma unroll
      for (int r = 0; r < 4; ++r) {
        int q = q0 + wave * 32 + sq * 16 + (lane >> 4) * 4 + r;
        int k = k0 + kb * 16 + (lane & 15);
        union { _Float16 h; unsigned short u; } cv;
        cv.h = (_Float16)log2f(zacc[sq][kb][r]);
        Zl[((size_t)b * S_ + q) * S_ + k] = cv.u;
      }
}

// ---------------- Pass 2: x^T = exp2(s*C - Lz) @ V ----------------
// Round-7: EXACT round-0 kernel (88.8 us measured; every structural variant in
// r1-r6 lost to it) + ONE lever: sched_group_barrier pinning the 8 prefetch
// VMEM reads (mask 0x20) to issue BEFORE the 8 QK MFMAs (0x8) each iteration.
// Diagnosis: VGPR_Count=64 across r0/r6 proves the named-register prefetch is
// collapsed by the compiler (c+n sets + qf + xacc need ~110 regs) -> loads are
// sunk to their use and every iteration exposes L2/L3 latency; ~40% of cycles
// unaccounted in r0 counters. SGB forces issue-early / complete-late.
// A/B signature: VGPR rises to ~100-130 if the pin takes effect.
__launch_bounds__(256, 3)
__global__ void attn_pv(const unsigned short* __restrict__ Qf,
                        const unsigned short* __restrict__ Kf,
                        const unsigned short* __restrict__ Vf,
                        const unsigned short* __restrict__ Zl,
                        unsigned short* __restrict__ X) {
  __shared__ unsigned short lP[2 * 4096];  // 2 bufs x (64q x 64k) fragment-ordered
  const int tid = threadIdx.x, lane = tid & 63, wave = tid >> 6;
  const int h = blockIdx.x, b = blockIdx.z;
  const int q0 = blockIdx.y * 64;

  const size_t headf = (size_t)(b * H_ + h) * (PERHEAD / 8);  // short8 units
  short8 qf[4][2];
#pragma unroll
  for (int qb = 0; qb < 4; ++qb) {
    const short8* qp = (const short8*)Qf + headf + ((q0 >> 4) + qb) * 128 + lane;
    qf[qb][0] = qp[0];
    qf[qb][1] = qp[64];
  }
  const short8* kp = (const short8*)Kf + headf + wave * 128 + lane;  // += 512/iter
  const short8* vp = (const short8*)Vf + headf + wave * 64 + lane;   // += 512/iter
  const unsigned short* zp = Zl + ((size_t)b * S_ + q0 + (lane & 15)) * S_
                             + wave * 16 + ((lane >> 4) << 2);

  // P write offset (ushort units, within one 4096 tile region): fragment-ordered
  const int pw_off = ((wave >> 1) << 9)
                   + (((lane & 15) | (((wave & 1) << 1 | ((lane >> 4) >> 1)) << 4)) << 3)
                   + (((lane >> 4) & 1) << 2);

  floatx4 xacc[4] = {};  // x^T[dk = wave*16 + row][q = qb*16 + col]

  // prologue: load iteration 0's operands
  short8 ck0 = kp[0], ck1 = kp[64];
  short8 cv0 = vp[0], cv1 = vp[256];
  uint2 cz0 = *(const uint2*)(zp);
  uint2 cz1 = *(const uint2*)(zp + (size_t)16 * S_);
  uint2 cz2 = *(const uint2*)(zp + (size_t)32 * S_);
  uint2 cz3 = *(const uint2*)(zp + (size_t)48 * S_);
  kp += 512; vp += 512; zp += 64;

#pragma unroll 2
  for (int kt = 0; kt < S_ / 64; ++kt) {
    const int buf = (kt & 1) << 12;
    // prefetch next iteration (named registers; guarded on last iter)
    short8 nk0, nk1, nv0, nv1;
    uint2 nz0, nz1, nz2, nz3;
    if (kt != S_ / 64 - 1) {
      nk0 = kp[0];  nk1 = kp[64];
      nv0 = vp[0];  nv1 = vp[256];
      nz0 = *(const uint2*)(zp);
      nz1 = *(const uint2*)(zp + (size_t)16 * S_);
      nz2 = *(const uint2*)(zp + (size_t)32 * S_);
      nz3 = *(const uint2*)(zp + (size_t)48 * S_);
      kp += 512; vp += 512; zp += 64;
    }

    // Pin schedule: 8 prefetch loads issue FIRST, then the 8 QK MFMAs.
    // (Without this, the compiler sinks the loads to their use -> latency exposed.)
    __builtin_amdgcn_sched_group_barrier(0x020, 8, 0);  // VMEM_READ x8
    __builtin_amdgcn_sched_group_barrier(0x008, 8, 0);  // MFMA x8 (QK)

    // S^T tiles: m = 16 keys (wave's), n = 64 q
    floatx4 sacc[4] = {};
#pragma unroll
    for (int qb = 0; qb < 4; ++qb) {
      sacc[qb] = MFMA16(ck0, qf[qb][0], sacc[qb]);
      sacc[qb] = MFMA16(ck1, qf[qb][1], sacc[qb]);
    }
    // P = exp2(s*C - Lz) -> bf16, fragment-ordered in LDS
#pragma unroll
    for (int qb = 0; qb < 4; ++qb) {
      uint2 zz = (qb == 0) ? cz0 : (qb == 1) ? cz1 : (qb == 2) ? cz2 : cz3;
      union { uint2 v; _Float16 hv[4]; } za; za.v = zz;
      float e0 = exp2f(fmaf(sacc[qb][0], EXP2SCALE, -(float)za.hv[0]));
      float e1 = exp2f(fmaf(sacc[qb][1], EXP2SCALE, -(float)za.hv[1]));
      float e2 = exp2f(fmaf(sacc[qb][2], EXP2SCALE, -(float)za.hv[2]));
      float e3 = exp2f(fmaf(sacc[qb][3], EXP2SCALE, -(float)za.hv[3]));
      uint2 p;
      p.x = pack_bf16_rhu(e0, e1);
      p.y = pack_bf16_rhu(e2, e3);
      *(uint2*)&lP[buf + (qb << 10) + pw_off] = p;
    }
    __syncthreads();

    // x^T += V_frag @ P  (conflict-free lane*16 reads)
#pragma unroll
    for (int qb = 0; qb < 4; ++qb) {
      short8 p0 = *(const short8*)&lP[buf + (qb << 10) + (lane << 3)];
      short8 p1 = *(const short8*)&lP[buf + (qb << 10) + 512 + (lane << 3)];
      xacc[qb] = MFMA16(cv0, p0, xacc[qb]);
      xacc[qb] = MFMA16(cv1, p1, xacc[qb]);
    }

    // rotate prefetched -> current (renames under unroll)
    ck0 = nk0; ck1 = nk1; cv0 = nv0; cv1 = nv1;
    cz0 = nz0; cz1 = nz1; cz2 = nz2; cz3 = nz3;
  }

  // epilogue: transpose x^T -> x via padded LDS, then coalesced 16B stores
  __syncthreads();
  unsigned short* lX = lP;  // 64 rows(q) x 72 (dk padded)
#pragma unroll
  for (int qb = 0; qb < 4; ++qb)
#pragma unroll
    for (int r = 0; r < 4; ++r) {
      int q  = qb * 16 + (lane & 15);
      int dk = wave * 16 + (lane >> 4) * 4 + r;
      lX[q * 72 + dk] = f2bf(xacc[qb][r]);
    }
  __syncthreads();
  {
    int q = tid >> 2, cg = (tid & 3) * 16;
    short8 v0 = *(const short8*)&lX[q * 72 + cg];
    short8 v1 = *(const short8*)&lX[q * 72 + cg + 8];
    unsigned short* o = X + (size_t)(b * S_ + q0 + q) * D_ + h * DK_ + cg;
    *(short8*)&o[0] = v0;
    *(short8*)&o[8] = v1;
  }
}

// ---------------- launch ----------------
extern "C" void kernel_launch(void* const* d_in, const int* in_sizes, int n_in,
                              void* d_out, int out_size, void* d_ws, size_t ws_size,
                              hipStream_t stream) {
  const float* qi = (const float*)d_in[0];
  const float* ki = (const float*)d_in[1];
  const float* vi = (const float*)d_in[2];
  // d_in[3] = mask: reference discards masked_fill result -> unused
  const float* Wq = (const float*)d_in[4];
  const float* Wk = (const float*)d_in[5];
  const float* Wv = (const float*)d_in[6];
  const float* Wo = (const float*)d_in[7];

  const size_t NT = (size_t)B_ * S_ * D_;  // 4,194,304
  const size_t NW = (size_t)D_ * D_;       // 1,048,576

  unsigned short* w = (unsigned short*)d_ws;
  unsigned short* qi_bf = w; w += NT;
  unsigned short* ki_bf = w; w += NT;
  unsigned short* vi_bf = w; w += NT;
  unsigned short* Wq_bf = w; w += NW;
  unsigned short* Wk_bf = w; w += NW;
  unsigned short* Wv_bf = w; w += NW;
  unsigned short* Wo_bf = w; w += NW;
  unsigned short* Qf = w; w += NT;  // fragment-ordered per (b,h)
  unsigned short* Kf = w; w += NT;
  unsigned short* Vf = w; w += NT;
  unsigned short* Xb = w; w += NT;  // [b,s,e] row-major bf16
  unsigned short* Zl = w;           // [b,q,k] fp16 log2(Z), 16 MiB

  {
    int n4 = (int)(NT / 4);   // 1048576 -> 4096 blocks
    cast3_f32_bf16<<<dim3((n4 + 255) / 256, 1, 3), 256, 0, stream>>>(
        qi, ki, vi, qi_bf, ki_bf, vi_bf, n4);
    int n4w = (int)(NW / 4);  // 262144 -> 1024 blocks
    cast4_f32_bf16<<<dim3((n4w + 255) / 256, 1, 4), 256, 0, stream>>>(
        Wq, Wk, Wv, Wo, Wq_bf, Wk_bf, Wv_bf, Wo_bf, n4w);
  }

  gemm_qkv<<<dim3(D_ / 128, (B_ * S_) / 128, 3), 256, 0, stream>>>(
      qi_bf, ki_bf, vi_bf, Wq_bf, Wk_bf, Wv_bf, Qf, Kf, Vf);

  compute_z<<<dim3(S_ / 128, S_ / 128, B_), 256, 0, stream>>>(Qf, Kf, Zl);
  attn_pv<<<dim3(H_, S_ / 64, B_), 256, 0, stream>>>(Qf, Kf, Vf, Zl, Xb);

  gemm_out<<<dim3(D_ / 128, (B_ * S_) / 128), 256, 0, stream>>>(Xb, Wo_bf, (float*)d_out);
}

// Round 8
// 306.032 us; speedup vs baseline: 1.1087x; 1.0234x over previous
//
#include <hip/hip_runtime.h>
#include <stdint.h>

// Problem constants (reference: B=2, S=2048, D=1024, H=16, DK=64)
#define B_  2
#define S_  2048
#define D_  1024
#define H_  16
#define DK_ 64
#define PERHEAD (S_ * DK_)  // 131072 elems per (b,h)

// exp(x*0.125) = exp2(x * 0.125*log2(e))
#define EXP2SCALE 0.18033688011112042f

typedef __attribute__((ext_vector_type(8))) short short8;   // 8 bf16 = 4 VGPRs (MFMA A/B frag)
typedef __attribute__((ext_vector_type(4))) float floatx4;  // MFMA C/D frag

#define MFMA16(a, b, c) __builtin_amdgcn_mfma_f32_16x16x32_bf16((a), (b), (c), 0, 0, 0)

// async global->LDS, 16B per lane (used only in the projection GEMMs)
__device__ __forceinline__ void gload_lds16(const void* g, void* lds) {
  __builtin_amdgcn_global_load_lds(
      (__attribute__((address_space(1))) void*)(void*)g,
      (__attribute__((address_space(3))) void*)lds, 16, 0, 0);
}

__device__ __forceinline__ unsigned short f2bf(float f) {
  union { float f; unsigned int u; } v;
  v.f = f;
  unsigned int r = v.u + 0x7fffu + ((v.u >> 16) & 1u);
  return (unsigned short)(r >> 16);
}

// pack two positive f32 into two bf16 (round-half-up: +0x8000 then take hi16 via v_perm)
__device__ __forceinline__ unsigned int pack_bf16_rhu(float e0, float e1) {
  unsigned int u0 = __float_as_uint(e0) + 0x8000u;
  unsigned int u1 = __float_as_uint(e1) + 0x8000u;
  return __builtin_amdgcn_perm(u1, u0, 0x07060302);  // {u1.hi16, u0.hi16}
}

// ---------------- batched casts fp32 -> bf16 (one launch for 3 inputs / 4 weights) ----
__global__ void cast3_f32_bf16(const float* __restrict__ a0, const float* __restrict__ a1,
                               const float* __restrict__ a2,
                               unsigned short* __restrict__ o0, unsigned short* __restrict__ o1,
                               unsigned short* __restrict__ o2, int n4) {
  const float* in = (blockIdx.z == 0) ? a0 : (blockIdx.z == 1) ? a1 : a2;
  unsigned short* out = (blockIdx.z == 0) ? o0 : (blockIdx.z == 1) ? o1 : o2;
  int i = blockIdx.x * 256 + threadIdx.x;
  if (i < n4) {
    float4 f = ((const float4*)in)[i];
    uint2 p;
    p.x = (unsigned int)f2bf(f.x) | ((unsigned int)f2bf(f.y) << 16);
    p.y = (unsigned int)f2bf(f.z) | ((unsigned int)f2bf(f.w) << 16);
    ((uint2*)out)[i] = p;
  }
}
__global__ void cast4_f32_bf16(const float* __restrict__ a0, const float* __restrict__ a1,
                               const float* __restrict__ a2, const float* __restrict__ a3,
                               unsigned short* __restrict__ o0, unsigned short* __restrict__ o1,
                               unsigned short* __restrict__ o2, unsigned short* __restrict__ o3,
                               int n4) {
  const float* in = (blockIdx.z == 0) ? a0 : (blockIdx.z == 1) ? a1 : (blockIdx.z == 2) ? a2 : a3;
  unsigned short* out = (blockIdx.z == 0) ? o0 : (blockIdx.z == 1) ? o1 : (blockIdx.z == 2) ? o2 : o3;
  int i = blockIdx.x * 256 + threadIdx.x;
  if (i < n4) {
    float4 f = ((const float4*)in)[i];
    uint2 p;
    p.x = (unsigned int)f2bf(f.x) | ((unsigned int)f2bf(f.y) << 16);
    p.y = (unsigned int)f2bf(f.z) | ((unsigned int)f2bf(f.w) << 16);
    ((uint2*)out)[i] = p;
  }
}

// Fragment-ordered layouts (16x16x32 MFMA operand fragments; one frag = 16 rows x
// 32 k x bf16 = 512 elems = 64 lane-ordered 16B chunks; chunk L = row(L&15),
// k = (L>>4)*8..+7). Reader: ds/global _b128 at base + lane*16 -> conflict-free.
//
// Qf/Kf per (b,h): frag(sblk = s>>4, ks = dk>>5):  idx = sblk*2 + ks
// Vf    per (b,h): frag(kblk = key>>5, db = dk>>4): idx = kblk*4 + db  (rows = dk)

// ---------------- shared GEMM core: 128x128 tile, BK=32, 4 waves each 64x64 ----------
__device__ __forceinline__ void gemm_core(const unsigned short* __restrict__ A,
                                          const unsigned short* __restrict__ Bw,
                                          unsigned short* lA, unsigned short* lB,
                                          int m0, int n0, int tid, int lane, int wave,
                                          floatx4 acc[4][4]) {
  const int wm = (wave >> 1) * 64;
  const int wn = (wave & 1) * 64;
  for (int k0 = 0; k0 < D_; k0 += 32) {
#pragma unroll
    for (int l = 0; l < 2; ++l) {
      int c = l * 256 + tid;
      int row = c >> 2, cb = (c & 3) * 16;
      const char* ga = (const char*)A + ((size_t)(m0 + row) * D_ + k0) * 2 + cb;
      gload_lds16(ga, (char*)lA + (size_t)(l * 256 + wave * 64) * 16);
      const char* gb = (const char*)Bw + ((size_t)(n0 + row) * D_ + k0) * 2 + cb;
      gload_lds16(gb, (char*)lB + (size_t)(l * 256 + wave * 64) * 16);
    }
    __syncthreads();
    short8 af[4], bf_[4];
#pragma unroll
    for (int mt = 0; mt < 4; ++mt)
      af[mt] = *(const short8*)&lA[(wm + mt * 16 + (lane & 15)) * 32 + (lane >> 4) * 8];
#pragma unroll
    for (int nt = 0; nt < 4; ++nt)
      bf_[nt] = *(const short8*)&lB[(wn + nt * 16 + (lane & 15)) * 32 + (lane >> 4) * 8];
#pragma unroll
    for (int mt = 0; mt < 4; ++mt)
#pragma unroll
      for (int nt = 0; nt < 4; ++nt)
        acc[mt][nt] = MFMA16(af[mt], bf_[nt], acc[mt][nt]);
    __syncthreads();
  }
}

// ---------------- fused QKV projection: z selects (A, W, Out, epilogue) ----------------
// Round-8: XCD swizzle (T1). Natural flat order f = x + 8y + 256z has f&7 = n-tile,
// so every XCD streams ALL of A (24 MB hot set). Remap: XCD owns m-tiles
// [xcd*4, xcd*4+4) for all n, z slowest -> hot set ~3 MB (A panel 1 MB + B 2 MB),
// L2-resident. Bijective: 768 = 8 xcd x 8 n x 4 m_loc x 3 z.
__launch_bounds__(256, 2)
__global__ void gemm_qkv(const unsigned short* __restrict__ qi, const unsigned short* __restrict__ ki,
                         const unsigned short* __restrict__ vi,
                         const unsigned short* __restrict__ Wq, const unsigned short* __restrict__ Wk,
                         const unsigned short* __restrict__ Wv,
                         unsigned short* __restrict__ Qf, unsigned short* __restrict__ Kf,
                         unsigned short* __restrict__ Vf) {
  __shared__ unsigned short lA[128 * 32];
  __shared__ unsigned short lB[128 * 32];
  const int f = blockIdx.x + 8 * blockIdx.y + 256 * blockIdx.z;
  const int xcd = f & 7, j = f >> 3;              // j in [0,96)
  const int n0 = (j & 7) * 128;                   // n-tile
  const int m0 = (xcd * 4 + ((j >> 3) & 3)) * 128;  // m-tile: XCD-chunked
  const int z  = j >> 5;                          // 0..2, slowest
  const unsigned short* A  = (z == 0) ? qi : (z == 1) ? ki : vi;
  const unsigned short* Bw = (z == 0) ? Wq : (z == 1) ? Wk : Wv;
  unsigned short* O        = (z == 0) ? Qf : (z == 1) ? Kf : Vf;
  const int tid = threadIdx.x, lane = tid & 63, wave = tid >> 6;
  const int wm = (wave >> 1) * 64, wn = (wave & 1) * 64;

  floatx4 acc[4][4] = {};
  gemm_core(A, Bw, lA, lB, m0, n0, tid, lane, wave, acc);

  if (z < 2) {  // Qf/Kf fragment layout
#pragma unroll
    for (int mt = 0; mt < 4; ++mt)
#pragma unroll
      for (int nt = 0; nt < 4; ++nt)
#pragma unroll
        for (int r = 0; r < 4; ++r) {
          int row = m0 + wm + mt * 16 + (lane >> 4) * 4 + r;  // token
          int col = n0 + wn + nt * 16 + (lane & 15);          // e
          int b = row >> 11, s = row & (S_ - 1);
          int h = col >> 6,  dk = col & 63;
          size_t base = (size_t)(b * H_ + h) * PERHEAD;
          int frag = (s >> 4) * 2 + (dk >> 5);
          int lp = (s & 15) | (((dk >> 3) & 3) << 4);
          O[base + (size_t)frag * 512 + lp * 8 + (dk & 7)] = f2bf(acc[mt][nt][r]);
        }
  } else {  // Vf fragment layout (rows = dk, k = key)
#pragma unroll
    for (int mt = 0; mt < 4; ++mt)
#pragma unroll
      for (int nt = 0; nt < 4; ++nt) {
        int row0 = m0 + wm + mt * 16 + (lane >> 4) * 4;  // 4 consecutive keys
        int col  = n0 + wn + nt * 16 + (lane & 15);
        int b = row0 >> 11, key0 = row0 & (S_ - 1);
        int h = col >> 6,   dk = col & 63;
        size_t base = (size_t)(b * H_ + h) * PERHEAD;
        int frag = (key0 >> 5) * 4 + (dk >> 4);
        int lp = (dk & 15) | (((key0 >> 3) & 3) << 4);
        unsigned long long pk =
            (unsigned long long)f2bf(acc[mt][nt][0]) |
            ((unsigned long long)f2bf(acc[mt][nt][1]) << 16) |
            ((unsigned long long)f2bf(acc[mt][nt][2]) << 32) |
            ((unsigned long long)f2bf(acc[mt][nt][3]) << 48);
        *(unsigned long long*)&O[base + (size_t)frag * 512 + lp * 8 + (key0 & 7)] = pk;
      }
  }
}

// ---------------- output projection: fp32 row-major ----------------
// Round-8: same XCD swizzle (256 = 8 xcd x 8 n x 4 m_loc).
__launch_bounds__(256, 2)
__global__ void gemm_out(const unsigned short* __restrict__ A, const unsigned short* __restrict__ Bw,
                         float* __restrict__ O) {
  __shared__ unsigned short lA[128 * 32];
  __shared__ unsigned short lB[128 * 32];
  const int f = blockIdx.x + 8 * blockIdx.y;
  const int xcd = f & 7, j = f >> 3;              // j in [0,32)
  const int n0 = (j & 7) * 128;
  const int m0 = (xcd * 4 + (j >> 3)) * 128;
  const int tid = threadIdx.x, lane = tid & 63, wave = tid >> 6;
  const int wm = (wave >> 1) * 64, wn = (wave & 1) * 64;
  floatx4 acc[4][4] = {};
  gemm_core(A, Bw, lA, lB, m0, n0, tid, lane, wave, acc);
#pragma unroll
  for (int mt = 0; mt < 4; ++mt)
#pragma unroll
    for (int nt = 0; nt < 4; ++nt)
#pragma unroll
      for (int r = 0; r < 4; ++r) {
        int row = m0 + wm + mt * 16 + (lane >> 4) * 4 + r;
        int col = n0 + wn + nt * 16 + (lane & 15);
        O[(size_t)row * D_ + col] = acc[mt][nt][r];
      }
}

// ---------------- Pass 1: Zl[b,q,k] = fp16( log2( sum_h exp2(s*C) ) ) ----------------
// Round-8: k-tile 128 -> 64. Old grid was 512 blocks = 2 blocks/CU (GRID-limited
// occupancy, 8 waves/CU) with a per-head dependent chain (12 loads -> 32 MFMA ->
// 64 exp) and no software pipeline -> latency-exposed, same pathology attn_pv had.
// 1024 blocks = 4 blocks/CU doubles the independent wave streams; register state
// halves (kst 64->32, zacc 64->32 VGPR) so (256,4) fits (~108 live < 128 cap).
// Cost: Q tiles re-read 2x (+16 MB, L2/L3-absorbed).
__launch_bounds__(256, 4)
__global__ void compute_z(const unsigned short* __restrict__ Qf,
                          const unsigned short* __restrict__ Kf,
                          unsigned short* __restrict__ Zl) {
  const int tid = threadIdx.x, lane = tid & 63, wave = tid >> 6;
  const int k0 = blockIdx.x * 64, q0 = blockIdx.y * 128, b = blockIdx.z;

  floatx4 zacc[2][4] = {};
  const short8* qbase = (const short8*)Qf + (size_t)b * H_ * (PERHEAD / 8)
                        + ((q0 >> 4) + wave * 2) * 128 + lane;
  const short8* kbase = (const short8*)Kf + (size_t)b * H_ * (PERHEAD / 8)
                        + (k0 >> 4) * 128 + lane;

#pragma unroll 1
  for (int h = 0; h < H_; ++h) {
    short8 qf0 = qbase[0], qf1 = qbase[64];    // sq=0, ks=0/1
    short8 qf2 = qbase[128], qf3 = qbase[192]; // sq=1, ks=0/1
    short8 kst[4][2];
#pragma unroll
    for (int kb = 0; kb < 4; ++kb) {
      kst[kb][0] = kbase[kb * 128];
      kst[kb][1] = kbase[kb * 128 + 64];
    }
#pragma unroll
    for (int kb = 0; kb < 4; ++kb) {
      floatx4 s0 = {}, s1 = {};
      s0 = MFMA16(qf0, kst[kb][0], s0);
      s0 = MFMA16(qf1, kst[kb][1], s0);
      s1 = MFMA16(qf2, kst[kb][0], s1);
      s1 = MFMA16(qf3, kst[kb][1], s1);
#pragma unroll
      for (int r = 0; r < 4; ++r) {
        zacc[0][kb][r] += exp2f(s0[r] * EXP2SCALE);
        zacc[1][kb][r] += exp2f(s1[r] * EXP2SCALE);
      }
    }
    qbase += PERHEAD / 8;
    kbase += PERHEAD / 8;
  }

#pragma unroll
  for (int sq = 0; sq < 2; ++sq)
#pragma unroll
    for (int kb = 0; kb < 4; ++kb)
#pragma unroll
      for (int r = 0; r < 4; ++r) {
        int q = q0 + wave * 32 + sq * 16 + (lane >> 4) * 4 + r;
        int k = k0 + kb * 16 + (lane & 15);
        union { _Float16 h; unsigned short u; } cv;
        cv.h = (_Float16)log2f(zacc[sq][kb][r]);
        Zl[((size_t)b * S_ + q) * S_ + k] = cv.u;
      }
}

// ---------------- Pass 2: x^T = exp2(s*C - Lz) @ V ----------------
// EXACT round-0 kernel (88.8 us, best measured across r0-r7; SGB pin was null,
// r7). attn_pv is at its structural floor; left as the control for this round.
// Head partition preserved (f mod 8 = h mod 8 -> 2 MB K/V per XCD, L2-resident).
__launch_bounds__(256, 3)
__global__ void attn_pv(const unsigned short* __restrict__ Qf,
                        const unsigned short* __restrict__ Kf,
                        const unsigned short* __restrict__ Vf,
                        const unsigned short* __restrict__ Zl,
                        unsigned short* __restrict__ X) {
  __shared__ unsigned short lP[2 * 4096];  // 2 bufs x (64q x 64k) fragment-ordered
  const int tid = threadIdx.x, lane = tid & 63, wave = tid >> 6;
  const int h = blockIdx.x, b = blockIdx.z;
  const int q0 = blockIdx.y * 64;

  const size_t headf = (size_t)(b * H_ + h) * (PERHEAD / 8);  // short8 units
  short8 qf[4][2];
#pragma unroll
  for (int qb = 0; qb < 4; ++qb) {
    const short8* qp = (const short8*)Qf + headf + ((q0 >> 4) + qb) * 128 + lane;
    qf[qb][0] = qp[0];
    qf[qb][1] = qp[64];
  }
  const short8* kp = (const short8*)Kf + headf + wave * 128 + lane;  // += 512/iter
  const short8* vp = (const short8*)Vf + headf + wave * 64 + lane;   // += 512/iter
  const unsigned short* zp = Zl + ((size_t)b * S_ + q0 + (lane & 15)) * S_
                             + wave * 16 + ((lane >> 4) << 2);

  // P write offset (ushort units, within one 4096 tile region): fragment-ordered
  const int pw_off = ((wave >> 1) << 9)
                   + (((lane & 15) | (((wave & 1) << 1 | ((lane >> 4) >> 1)) << 4)) << 3)
                   + (((lane >> 4) & 1) << 2);

  floatx4 xacc[4] = {};  // x^T[dk = wave*16 + row][q = qb*16 + col]

  // prologue: load iteration 0's operands
  short8 ck0 = kp[0], ck1 = kp[64];
  short8 cv0 = vp[0], cv1 = vp[256];
  uint2 cz0 = *(const uint2*)(zp);
  uint2 cz1 = *(const uint2*)(zp + (size_t)16 * S_);
  uint2 cz2 = *(const uint2*)(zp + (size_t)32 * S_);
  uint2 cz3 = *(const uint2*)(zp + (size_t)48 * S_);
  kp += 512; vp += 512; zp += 64;

#pragma unroll 2
  for (int kt = 0; kt < S_ / 64; ++kt) {
    const int buf = (kt & 1) << 12;
    // prefetch next iteration (named registers; guarded on last iter)
    short8 nk0, nk1, nv0, nv1;
    uint2 nz0, nz1, nz2, nz3;
    if (kt != S_ / 64 - 1) {
      nk0 = kp[0];  nk1 = kp[64];
      nv0 = vp[0];  nv1 = vp[256];
      nz0 = *(const uint2*)(zp);
      nz1 = *(const uint2*)(zp + (size_t)16 * S_);
      nz2 = *(const uint2*)(zp + (size_t)32 * S_);
      nz3 = *(const uint2*)(zp + (size_t)48 * S_);
      kp += 512; vp += 512; zp += 64;
    }

    // S^T tiles: m = 16 keys (wave's), n = 64 q
    floatx4 sacc[4] = {};
#pragma unroll
    for (int qb = 0; qb < 4; ++qb) {
      sacc[qb] = MFMA16(ck0, qf[qb][0], sacc[qb]);
      sacc[qb] = MFMA16(ck1, qf[qb][1], sacc[qb]);
    }
    // P = exp2(s*C - Lz) -> bf16, fragment-ordered in LDS
#pragma unroll
    for (int qb = 0; qb < 4; ++qb) {
      uint2 zz = (qb == 0) ? cz0 : (qb == 1) ? cz1 : (qb == 2) ? cz2 : cz3;
      union { uint2 v; _Float16 hv[4]; } za; za.v = zz;
      float e0 = exp2f(fmaf(sacc[qb][0], EXP2SCALE, -(float)za.hv[0]));
      float e1 = exp2f(fmaf(sacc[qb][1], EXP2SCALE, -(float)za.hv[1]));
      float e2 = exp2f(fmaf(sacc[qb][2], EXP2SCALE, -(float)za.hv[2]));
      float e3 = exp2f(fmaf(sacc[qb][3], EXP2SCALE, -(float)za.hv[3]));
      uint2 p;
      p.x = pack_bf16_rhu(e0, e1);
      p.y = pack_bf16_rhu(e2, e3);
      *(uint2*)&lP[buf + (qb << 10) + pw_off] = p;
    }
    __syncthreads();

    // x^T += V_frag @ P  (conflict-free lane*16 reads)
#pragma unroll
    for (int qb = 0; qb < 4; ++qb) {
      short8 p0 = *(const short8*)&lP[buf + (qb << 10) + (lane << 3)];
      short8 p1 = *(const short8*)&lP[buf + (qb << 10) + 512 + (lane << 3)];
      xacc[qb] = MFMA16(cv0, p0, xacc[qb]);
      xacc[qb] = MFMA16(cv1, p1, xacc[qb]);
    }

    // rotate prefetched -> current (renames under unroll)
    ck0 = nk0; ck1 = nk1; cv0 = nv0; cv1 = nv1;
    cz0 = nz0; cz1 = nz1; cz2 = nz2; cz3 = nz3;
  }

  // epilogue: transpose x^T -> x via padded LDS, then coalesced 16B stores
  __syncthreads();
  unsigned short* lX = lP;  // 64 rows(q) x 72 (dk padded)
#pragma unroll
  for (int qb = 0; qb < 4; ++qb)
#pragma unroll
    for (int r = 0; r < 4; ++r) {
      int q  = qb * 16 + (lane & 15);
      int dk = wave * 16 + (lane >> 4) * 4 + r;
      lX[q * 72 + dk] = f2bf(xacc[qb][r]);
    }
  __syncthreads();
  {
    int q = tid >> 2, cg = (tid & 3) * 16;
    short8 v0 = *(const short8*)&lX[q * 72 + cg];
    short8 v1 = *(const short8*)&lX[q * 72 + cg + 8];
    unsigned short* o = X + (size_t)(b * S_ + q0 + q) * D_ + h * DK_ + cg;
    *(short8*)&o[0] = v0;
    *(short8*)&o[8] = v1;
  }
}

// ---------------- launch ----------------
extern "C" void kernel_launch(void* const* d_in, const int* in_sizes, int n_in,
                              void* d_out, int out_size, void* d_ws, size_t ws_size,
                              hipStream_t stream) {
  const float* qi = (const float*)d_in[0];
  const float* ki = (const float*)d_in[1];
  const float* vi = (const float*)d_in[2];
  // d_in[3] = mask: reference discards masked_fill result -> unused
  const float* Wq = (const float*)d_in[4];
  const float* Wk = (const float*)d_in[5];
  const float* Wv = (const float*)d_in[6];
  const float* Wo = (const float*)d_in[7];

  const size_t NT = (size_t)B_ * S_ * D_;  // 4,194,304
  const size_t NW = (size_t)D_ * D_;       // 1,048,576

  unsigned short* w = (unsigned short*)d_ws;
  unsigned short* qi_bf = w; w += NT;
  unsigned short* ki_bf = w; w += NT;
  unsigned short* vi_bf = w; w += NT;
  unsigned short* Wq_bf = w; w += NW;
  unsigned short* Wk_bf = w; w += NW;
  unsigned short* Wv_bf = w; w += NW;
  unsigned short* Wo_bf = w; w += NW;
  unsigned short* Qf = w; w += NT;  // fragment-ordered per (b,h)
  unsigned short* Kf = w; w += NT;
  unsigned short* Vf = w; w += NT;
  unsigned short* Xb = w; w += NT;  // [b,s,e] row-major bf16
  unsigned short* Zl = w;           // [b,q,k] fp16 log2(Z), 16 MiB

  {
    int n4 = (int)(NT / 4);   // 1048576 -> 4096 blocks
    cast3_f32_bf16<<<dim3((n4 + 255) / 256, 1, 3), 256, 0, stream>>>(
        qi, ki, vi, qi_bf, ki_bf, vi_bf, n4);
    int n4w = (int)(NW / 4);  // 262144 -> 1024 blocks
    cast4_f32_bf16<<<dim3((n4w + 255) / 256, 1, 4), 256, 0, stream>>>(
        Wq, Wk, Wv, Wo, Wq_bf, Wk_bf, Wv_bf, Wo_bf, n4w);
  }

  gemm_qkv<<<dim3(D_ / 128, (B_ * S_) / 128, 3), 256, 0, stream>>>(
      qi_bf, ki_bf, vi_bf, Wq_bf, Wk_bf, Wv_bf, Qf, Kf, Vf);

  compute_z<<<dim3(S_ / 64, S_ / 128, B_), 256, 0, stream>>>(Qf, Kf, Zl);
  attn_pv<<<dim3(H_, S_ / 64, B_), 256, 0, stream>>>(Qf, Kf, Vf, Zl, Xb);

  gemm_out<<<dim3(D_ / 128, (B_ * S_) / 128), 256, 0, stream>>>(Xb, Wo_bf, (float*)d_out);
}

// Round 9
// 303.930 us; speedup vs baseline: 1.1163x; 1.0069x over previous
//
#include <hip/hip_runtime.h>
#include <stdint.h>

// Problem constants (reference: B=2, S=2048, D=1024, H=16, DK=64)
#define B_  2
#define S_  2048
#define D_  1024
#define H_  16
#define DK_ 64
#define PERHEAD (S_ * DK_)  // 131072 elems per (b,h)

// exp(x*0.125) = exp2(x * 0.125*log2(e))
#define EXP2SCALE 0.18033688011112042f

typedef __attribute__((ext_vector_type(8))) short short8;   // 8 bf16 = 4 VGPRs (MFMA A/B frag)
typedef __attribute__((ext_vector_type(4))) float floatx4;  // MFMA C/D frag

#define MFMA16(a, b, c) __builtin_amdgcn_mfma_f32_16x16x32_bf16((a), (b), (c), 0, 0, 0)

// async global->LDS, 16B per lane (used only in the projection GEMMs)
__device__ __forceinline__ void gload_lds16(const void* g, void* lds) {
  __builtin_amdgcn_global_load_lds(
      (__attribute__((address_space(1))) void*)(void*)g,
      (__attribute__((address_space(3))) void*)lds, 16, 0, 0);
}

__device__ __forceinline__ unsigned short f2bf(float f) {
  union { float f; unsigned int u; } v;
  v.f = f;
  unsigned int r = v.u + 0x7fffu + ((v.u >> 16) & 1u);
  return (unsigned short)(r >> 16);
}

// pack two positive f32 into two bf16 (round-half-up: +0x8000 then take hi16 via v_perm)
__device__ __forceinline__ unsigned int pack_bf16_rhu(float e0, float e1) {
  unsigned int u0 = __float_as_uint(e0) + 0x8000u;
  unsigned int u1 = __float_as_uint(e1) + 0x8000u;
  return __builtin_amdgcn_perm(u1, u0, 0x07060302);  // {u1.hi16, u0.hi16}
}

// ---------------- batched casts fp32 -> bf16 (one launch for 3 inputs / 4 weights) ----
__global__ void cast3_f32_bf16(const float* __restrict__ a0, const float* __restrict__ a1,
                               const float* __restrict__ a2,
                               unsigned short* __restrict__ o0, unsigned short* __restrict__ o1,
                               unsigned short* __restrict__ o2, int n4) {
  const float* in = (blockIdx.z == 0) ? a0 : (blockIdx.z == 1) ? a1 : a2;
  unsigned short* out = (blockIdx.z == 0) ? o0 : (blockIdx.z == 1) ? o1 : o2;
  int i = blockIdx.x * 256 + threadIdx.x;
  if (i < n4) {
    float4 f = ((const float4*)in)[i];
    uint2 p;
    p.x = (unsigned int)f2bf(f.x) | ((unsigned int)f2bf(f.y) << 16);
    p.y = (unsigned int)f2bf(f.z) | ((unsigned int)f2bf(f.w) << 16);
    ((uint2*)out)[i] = p;
  }
}
__global__ void cast4_f32_bf16(const float* __restrict__ a0, const float* __restrict__ a1,
                               const float* __restrict__ a2, const float* __restrict__ a3,
                               unsigned short* __restrict__ o0, unsigned short* __restrict__ o1,
                               unsigned short* __restrict__ o2, unsigned short* __restrict__ o3,
                               int n4) {
  const float* in = (blockIdx.z == 0) ? a0 : (blockIdx.z == 1) ? a1 : (blockIdx.z == 2) ? a2 : a3;
  unsigned short* out = (blockIdx.z == 0) ? o0 : (blockIdx.z == 1) ? o1 : (blockIdx.z == 2) ? o2 : o3;
  int i = blockIdx.x * 256 + threadIdx.x;
  if (i < n4) {
    float4 f = ((const float4*)in)[i];
    uint2 p;
    p.x = (unsigned int)f2bf(f.x) | ((unsigned int)f2bf(f.y) << 16);
    p.y = (unsigned int)f2bf(f.z) | ((unsigned int)f2bf(f.w) << 16);
    ((uint2*)out)[i] = p;
  }
}

// Fragment-ordered layouts (16x16x32 MFMA operand fragments; one frag = 16 rows x
// 32 k x bf16 = 512 elems = 64 lane-ordered 16B chunks; chunk L = row(L&15),
// k = (L>>4)*8..+7). Reader: ds/global _b128 at base + lane*16 -> conflict-free.
//
// Qf/Kf per (b,h): frag(sblk = s>>4, ks = dk>>5):  idx = sblk*2 + ks
// Vf    per (b,h): frag(kblk = key>>5, db = dk>>4): idx = kblk*4 + db  (rows = dk)

// ---------------- shared GEMM core: 128x128 tile, BK=32, 4 waves each 64x64 ----------
__device__ __forceinline__ void gemm_core(const unsigned short* __restrict__ A,
                                          const unsigned short* __restrict__ Bw,
                                          unsigned short* lA, unsigned short* lB,
                                          int m0, int n0, int tid, int lane, int wave,
                                          floatx4 acc[4][4]) {
  const int wm = (wave >> 1) * 64;
  const int wn = (wave & 1) * 64;
  for (int k0 = 0; k0 < D_; k0 += 32) {
#pragma unroll
    for (int l = 0; l < 2; ++l) {
      int c = l * 256 + tid;
      int row = c >> 2, cb = (c & 3) * 16;
      const char* ga = (const char*)A + ((size_t)(m0 + row) * D_ + k0) * 2 + cb;
      gload_lds16(ga, (char*)lA + (size_t)(l * 256 + wave * 64) * 16);
      const char* gb = (const char*)Bw + ((size_t)(n0 + row) * D_ + k0) * 2 + cb;
      gload_lds16(gb, (char*)lB + (size_t)(l * 256 + wave * 64) * 16);
    }
    __syncthreads();
    short8 af[4], bf_[4];
#pragma unroll
    for (int mt = 0; mt < 4; ++mt)
      af[mt] = *(const short8*)&lA[(wm + mt * 16 + (lane & 15)) * 32 + (lane >> 4) * 8];
#pragma unroll
    for (int nt = 0; nt < 4; ++nt)
      bf_[nt] = *(const short8*)&lB[(wn + nt * 16 + (lane & 15)) * 32 + (lane >> 4) * 8];
#pragma unroll
    for (int mt = 0; mt < 4; ++mt)
#pragma unroll
      for (int nt = 0; nt < 4; ++nt)
        acc[mt][nt] = MFMA16(af[mt], bf_[nt], acc[mt][nt]);
    __syncthreads();
  }
}

// ---------------- fused QKV projection: z selects (A, W, Out, epilogue) ----------------
// XCD swizzle (r8): XCD owns m-tiles [xcd*4, xcd*4+4) for all n, z slowest ->
// hot set ~3 MB (A panel 1 MB + B 2 MB), L2-resident. 768 = 8 xcd x 8 n x 4 m x 3 z.
// Round-9: (256,2) -> (256,3). Grid provides exactly 3 blocks/CU; the old bound
// capped residency at 2, leaving the third block queued -> 2-deep instead of
// 3-deep implicit wave overlap (the m97 structure relies on 3/CU; m114).
// Spill signature to watch: WRITE_SIZE balloon (VGPR cap 168, live ~120).
__launch_bounds__(256, 3)
__global__ void gemm_qkv(const unsigned short* __restrict__ qi, const unsigned short* __restrict__ ki,
                         const unsigned short* __restrict__ vi,
                         const unsigned short* __restrict__ Wq, const unsigned short* __restrict__ Wk,
                         const unsigned short* __restrict__ Wv,
                         unsigned short* __restrict__ Qf, unsigned short* __restrict__ Kf,
                         unsigned short* __restrict__ Vf) {
  __shared__ unsigned short lA[128 * 32];
  __shared__ unsigned short lB[128 * 32];
  const int f = blockIdx.x + 8 * blockIdx.y + 256 * blockIdx.z;
  const int xcd = f & 7, j = f >> 3;              // j in [0,96)
  const int n0 = (j & 7) * 128;                   // n-tile
  const int m0 = (xcd * 4 + ((j >> 3) & 3)) * 128;  // m-tile: XCD-chunked
  const int z  = j >> 5;                          // 0..2, slowest
  const unsigned short* A  = (z == 0) ? qi : (z == 1) ? ki : vi;
  const unsigned short* Bw = (z == 0) ? Wq : (z == 1) ? Wk : Wv;
  unsigned short* O        = (z == 0) ? Qf : (z == 1) ? Kf : Vf;
  const int tid = threadIdx.x, lane = tid & 63, wave = tid >> 6;
  const int wm = (wave >> 1) * 64, wn = (wave & 1) * 64;

  floatx4 acc[4][4] = {};
  gemm_core(A, Bw, lA, lB, m0, n0, tid, lane, wave, acc);

  if (z < 2) {  // Qf/Kf fragment layout
#pragma unroll
    for (int mt = 0; mt < 4; ++mt)
#pragma unroll
      for (int nt = 0; nt < 4; ++nt)
#pragma unroll
        for (int r = 0; r < 4; ++r) {
          int row = m0 + wm + mt * 16 + (lane >> 4) * 4 + r;  // token
          int col = n0 + wn + nt * 16 + (lane & 15);          // e
          int b = row >> 11, s = row & (S_ - 1);
          int h = col >> 6,  dk = col & 63;
          size_t base = (size_t)(b * H_ + h) * PERHEAD;
          int frag = (s >> 4) * 2 + (dk >> 5);
          int lp = (s & 15) | (((dk >> 3) & 3) << 4);
          O[base + (size_t)frag * 512 + lp * 8 + (dk & 7)] = f2bf(acc[mt][nt][r]);
        }
  } else {  // Vf fragment layout (rows = dk, k = key)
#pragma unroll
    for (int mt = 0; mt < 4; ++mt)
#pragma unroll
      for (int nt = 0; nt < 4; ++nt) {
        int row0 = m0 + wm + mt * 16 + (lane >> 4) * 4;  // 4 consecutive keys
        int col  = n0 + wn + nt * 16 + (lane & 15);
        int b = row0 >> 11, key0 = row0 & (S_ - 1);
        int h = col >> 6,   dk = col & 63;
        size_t base = (size_t)(b * H_ + h) * PERHEAD;
        int frag = (key0 >> 5) * 4 + (dk >> 4);
        int lp = (dk & 15) | (((key0 >> 3) & 3) << 4);
        unsigned long long pk =
            (unsigned long long)f2bf(acc[mt][nt][0]) |
            ((unsigned long long)f2bf(acc[mt][nt][1]) << 16) |
            ((unsigned long long)f2bf(acc[mt][nt][2]) << 32) |
            ((unsigned long long)f2bf(acc[mt][nt][3]) << 48);
        *(unsigned long long*)&O[base + (size_t)frag * 512 + lp * 8 + (key0 & 7)] = pk;
      }
  }
}

// ---------------- output projection: fp32 row-major ----------------
// Round-9: 64x128 tile (was 128x128). Old grid = 256 blocks = 1 block/CU =
// 1 wave/SIMD -> staging + barrier drain fully exposed. New: 512 blocks = 2/CU.
// 4 waves each 32x64 (acc[2][4]); per K-step: 1 A-chunk + 2 B-chunks per thread.
// XCD swizzle: XCD owns m-tiles [xcd*8, xcd*8+8) = 512 rows (1 MB A) + B 2 MB.
__launch_bounds__(256, 2)
__global__ void gemm_out(const unsigned short* __restrict__ A, const unsigned short* __restrict__ Bw,
                         float* __restrict__ O) {
  __shared__ unsigned short lA[64 * 32];
  __shared__ unsigned short lB[128 * 32];
  const int f = blockIdx.x + 8 * blockIdx.y;      // grid (8, 64) = 512 blocks
  const int xcd = f & 7, j = f >> 3;              // j in [0,64)
  const int n0 = (j & 7) * 128;
  const int m0 = (xcd * 8 + (j >> 3)) * 64;       // m-tile (64 rows): XCD-chunked
  const int tid = threadIdx.x, lane = tid & 63, wave = tid >> 6;
  const int wm = (wave >> 1) * 32, wn = (wave & 1) * 64;
  floatx4 acc[2][4] = {};
  for (int k0 = 0; k0 < D_; k0 += 32) {
    {  // A: 64x32 tile = 256 x 16B chunks, one per thread
      int c = tid;
      int row = c >> 2, cb = (c & 3) * 16;
      const char* ga = (const char*)A + ((size_t)(m0 + row) * D_ + k0) * 2 + cb;
      gload_lds16(ga, (char*)lA + (size_t)(wave * 64) * 16);
    }
#pragma unroll
    for (int l = 0; l < 2; ++l) {  // B: 128x32 tile = 512 chunks, two per thread
      int c = l * 256 + tid;
      int row = c >> 2, cb = (c & 3) * 16;
      const char* gb = (const char*)Bw + ((size_t)(n0 + row) * D_ + k0) * 2 + cb;
      gload_lds16(gb, (char*)lB + (size_t)(l * 256 + wave * 64) * 16);
    }
    __syncthreads();
    short8 af[2], bf_[4];
#pragma unroll
    for (int mt = 0; mt < 2; ++mt)
      af[mt] = *(const short8*)&lA[(wm + mt * 16 + (lane & 15)) * 32 + (lane >> 4) * 8];
#pragma unroll
    for (int nt = 0; nt < 4; ++nt)
      bf_[nt] = *(const short8*)&lB[(wn + nt * 16 + (lane & 15)) * 32 + (lane >> 4) * 8];
#pragma unroll
    for (int mt = 0; mt < 2; ++mt)
#pragma unroll
      for (int nt = 0; nt < 4; ++nt)
        acc[mt][nt] = MFMA16(af[mt], bf_[nt], acc[mt][nt]);
    __syncthreads();
  }
#pragma unroll
  for (int mt = 0; mt < 2; ++mt)
#pragma unroll
    for (int nt = 0; nt < 4; ++nt)
#pragma unroll
      for (int r = 0; r < 4; ++r) {
        int row = m0 + wm + mt * 16 + (lane >> 4) * 4 + r;
        int col = n0 + wn + nt * 16 + (lane & 15);
        O[(size_t)row * D_ + col] = acc[mt][nt][r];
      }
}

// ---------------- Pass 1: Zl[b,q,k] = fp16( log2( sum_h exp2(s*C) ) ) ----------------
// r8: k-tile 64, 1024 blocks = 4 blocks/CU, (256,4). Kept as-is (part of the
// measured 306.0 best).
__launch_bounds__(256, 4)
__global__ void compute_z(const unsigned short* __restrict__ Qf,
                          const unsigned short* __restrict__ Kf,
                          unsigned short* __restrict__ Zl) {
  const int tid = threadIdx.x, lane = tid & 63, wave = tid >> 6;
  const int k0 = blockIdx.x * 64, q0 = blockIdx.y * 128, b = blockIdx.z;

  floatx4 zacc[2][4] = {};
  const short8* qbase = (const short8*)Qf + (size_t)b * H_ * (PERHEAD / 8)
                        + ((q0 >> 4) + wave * 2) * 128 + lane;
  const short8* kbase = (const short8*)Kf + (size_t)b * H_ * (PERHEAD / 8)
                        + (k0 >> 4) * 128 + lane;

#pragma unroll 1
  for (int h = 0; h < H_; ++h) {
    short8 qf0 = qbase[0], qf1 = qbase[64];    // sq=0, ks=0/1
    short8 qf2 = qbase[128], qf3 = qbase[192]; // sq=1, ks=0/1
    short8 kst[4][2];
#pragma unroll
    for (int kb = 0; kb < 4; ++kb) {
      kst[kb][0] = kbase[kb * 128];
      kst[kb][1] = kbase[kb * 128 + 64];
    }
#pragma unroll
    for (int kb = 0; kb < 4; ++kb) {
      floatx4 s0 = {}, s1 = {};
      s0 = MFMA16(qf0, kst[kb][0], s0);
      s0 = MFMA16(qf1, kst[kb][1], s0);
      s1 = MFMA16(qf2, kst[kb][0], s1);
      s1 = MFMA16(qf3, kst[kb][1], s1);
#pragma unroll
      for (int r = 0; r < 4; ++r) {
        zacc[0][kb][r] += exp2f(s0[r] * EXP2SCALE);
        zacc[1][kb][r] += exp2f(s1[r] * EXP2SCALE);
      }
    }
    qbase += PERHEAD / 8;
    kbase += PERHEAD / 8;
  }

#pragma unroll
  for (int sq = 0; sq < 2; ++sq)
#pragma unroll
    for (int kb = 0; kb < 4; ++kb)
#pragma unroll
      for (int r = 0; r < 4; ++r) {
        int q = q0 + wave * 32 + sq * 16 + (lane >> 4) * 4 + r;
        int k = k0 + kb * 16 + (lane & 15);
        union { _Float16 h; unsigned short u; } cv;
        cv.h = (_Float16)log2f(zacc[sq][kb][r]);
        Zl[((size_t)b * S_ + q) * S_ + k] = cv.u;
      }
}

// ---------------- Pass 2: x^T = exp2(s*C - Lz) @ V ----------------
// EXACT round-0 kernel (88.8-90.7 us, best measured across r0-r8; structural
// floor for this family — 7 variants all lost). Control for this round.
// Head partition preserved (f mod 8 = h mod 8 -> 2 MB K/V per XCD, L2-resident).
__launch_bounds__(256, 3)
__global__ void attn_pv(const unsigned short* __restrict__ Qf,
                        const unsigned short* __restrict__ Kf,
                        const unsigned short* __restrict__ Vf,
                        const unsigned short* __restrict__ Zl,
                        unsigned short* __restrict__ X) {
  __shared__ unsigned short lP[2 * 4096];  // 2 bufs x (64q x 64k) fragment-ordered
  const int tid = threadIdx.x, lane = tid & 63, wave = tid >> 6;
  const int h = blockIdx.x, b = blockIdx.z;
  const int q0 = blockIdx.y * 64;

  const size_t headf = (size_t)(b * H_ + h) * (PERHEAD / 8);  // short8 units
  short8 qf[4][2];
#pragma unroll
  for (int qb = 0; qb < 4; ++qb) {
    const short8* qp = (const short8*)Qf + headf + ((q0 >> 4) + qb) * 128 + lane;
    qf[qb][0] = qp[0];
    qf[qb][1] = qp[64];
  }
  const short8* kp = (const short8*)Kf + headf + wave * 128 + lane;  // += 512/iter
  const short8* vp = (const short8*)Vf + headf + wave * 64 + lane;   // += 512/iter
  const unsigned short* zp = Zl + ((size_t)b * S_ + q0 + (lane & 15)) * S_
                             + wave * 16 + ((lane >> 4) << 2);

  // P write offset (ushort units, within one 4096 tile region): fragment-ordered
  const int pw_off = ((wave >> 1) << 9)
                   + (((lane & 15) | (((wave & 1) << 1 | ((lane >> 4) >> 1)) << 4)) << 3)
                   + (((lane >> 4) & 1) << 2);

  floatx4 xacc[4] = {};  // x^T[dk = wave*16 + row][q = qb*16 + col]

  // prologue: load iteration 0's operands
  short8 ck0 = kp[0], ck1 = kp[64];
  short8 cv0 = vp[0], cv1 = vp[256];
  uint2 cz0 = *(const uint2*)(zp);
  uint2 cz1 = *(const uint2*)(zp + (size_t)16 * S_);
  uint2 cz2 = *(const uint2*)(zp + (size_t)32 * S_);
  uint2 cz3 = *(const uint2*)(zp + (size_t)48 * S_);
  kp += 512; vp += 512; zp += 64;

#pragma unroll 2
  for (int kt = 0; kt < S_ / 64; ++kt) {
    const int buf = (kt & 1) << 12;
    // prefetch next iteration (named registers; guarded on last iter)
    short8 nk0, nk1, nv0, nv1;
    uint2 nz0, nz1, nz2, nz3;
    if (kt != S_ / 64 - 1) {
      nk0 = kp[0];  nk1 = kp[64];
      nv0 = vp[0];  nv1 = vp[256];
      nz0 = *(const uint2*)(zp);
      nz1 = *(const uint2*)(zp + (size_t)16 * S_);
      nz2 = *(const uint2*)(zp + (size_t)32 * S_);
      nz3 = *(const uint2*)(zp + (size_t)48 * S_);
      kp += 512; vp += 512; zp += 64;
    }

    // S^T tiles: m = 16 keys (wave's), n = 64 q
    floatx4 sacc[4] = {};
#pragma unroll
    for (int qb = 0; qb < 4; ++qb) {
      sacc[qb] = MFMA16(ck0, qf[qb][0], sacc[qb]);
      sacc[qb] = MFMA16(ck1, qf[qb][1], sacc[qb]);
    }
    // P = exp2(s*C - Lz) -> bf16, fragment-ordered in LDS
#pragma unroll
    for (int qb = 0; qb < 4; ++qb) {
      uint2 zz = (qb == 0) ? cz0 : (qb == 1) ? cz1 : (qb == 2) ? cz2 : cz3;
      union { uint2 v; _Float16 hv[4]; } za; za.v = zz;
      float e0 = exp2f(fmaf(sacc[qb][0], EXP2SCALE, -(float)za.hv[0]));
      float e1 = exp2f(fmaf(sacc[qb][1], EXP2SCALE, -(float)za.hv[1]));
      float e2 = exp2f(fmaf(sacc[qb][2], EXP2SCALE, -(float)za.hv[2]));
      float e3 = exp2f(fmaf(sacc[qb][3], EXP2SCALE, -(float)za.hv[3]));
      uint2 p;
      p.x = pack_bf16_rhu(e0, e1);
      p.y = pack_bf16_rhu(e2, e3);
      *(uint2*)&lP[buf + (qb << 10) + pw_off] = p;
    }
    __syncthreads();

    // x^T += V_frag @ P  (conflict-free lane*16 reads)
#pragma unroll
    for (int qb = 0; qb < 4; ++qb) {
      short8 p0 = *(const short8*)&lP[buf + (qb << 10) + (lane << 3)];
      short8 p1 = *(const short8*)&lP[buf + (qb << 10) + 512 + (lane << 3)];
      xacc[qb] = MFMA16(cv0, p0, xacc[qb]);
      xacc[qb] = MFMA16(cv1, p1, xacc[qb]);
    }

    // rotate prefetched -> current (renames under unroll)
    ck0 = nk0; ck1 = nk1; cv0 = nv0; cv1 = nv1;
    cz0 = nz0; cz1 = nz1; cz2 = nz2; cz3 = nz3;
  }

  // epilogue: transpose x^T -> x via padded LDS, then coalesced 16B stores
  __syncthreads();
  unsigned short* lX = lP;  // 64 rows(q) x 72 (dk padded)
#pragma unroll
  for (int qb = 0; qb < 4; ++qb)
#pragma unroll
    for (int r = 0; r < 4; ++r) {
      int q  = qb * 16 + (lane & 15);
      int dk = wave * 16 + (lane >> 4) * 4 + r;
      lX[q * 72 + dk] = f2bf(xacc[qb][r]);
    }
  __syncthreads();
  {
    int q = tid >> 2, cg = (tid & 3) * 16;
    short8 v0 = *(const short8*)&lX[q * 72 + cg];
    short8 v1 = *(const short8*)&lX[q * 72 + cg + 8];
    unsigned short* o = X + (size_t)(b * S_ + q0 + q) * D_ + h * DK_ + cg;
    *(short8*)&o[0] = v0;
    *(short8*)&o[8] = v1;
  }
}

// ---------------- launch ----------------
extern "C" void kernel_launch(void* const* d_in, const int* in_sizes, int n_in,
                              void* d_out, int out_size, void* d_ws, size_t ws_size,
                              hipStream_t stream) {
  const float* qi = (const float*)d_in[0];
  const float* ki = (const float*)d_in[1];
  const float* vi = (const float*)d_in[2];
  // d_in[3] = mask: reference discards masked_fill result -> unused
  const float* Wq = (const float*)d_in[4];
  const float* Wk = (const float*)d_in[5];
  const float* Wv = (const float*)d_in[6];
  const float* Wo = (const float*)d_in[7];

  const size_t NT = (size_t)B_ * S_ * D_;  // 4,194,304
  const size_t NW = (size_t)D_ * D_;       // 1,048,576

  unsigned short* w = (unsigned short*)d_ws;
  unsigned short* qi_bf = w; w += NT;
  unsigned short* ki_bf = w; w += NT;
  unsigned short* vi_bf = w; w += NT;
  unsigned short* Wq_bf = w; w += NW;
  unsigned short* Wk_bf = w; w += NW;
  unsigned short* Wv_bf = w; w += NW;
  unsigned short* Wo_bf = w; w += NW;
  unsigned short* Qf = w; w += NT;  // fragment-ordered per (b,h)
  unsigned short* Kf = w; w += NT;
  unsigned short* Vf = w; w += NT;
  unsigned short* Xb = w; w += NT;  // [b,s,e] row-major bf16
  unsigned short* Zl = w;           // [b,q,k] fp16 log2(Z), 16 MiB

  {
    int n4 = (int)(NT / 4);   // 1048576 -> 4096 blocks
    cast3_f32_bf16<<<dim3((n4 + 255) / 256, 1, 3), 256, 0, stream>>>(
        qi, ki, vi, qi_bf, ki_bf, vi_bf, n4);
    int n4w = (int)(NW / 4);  // 262144 -> 1024 blocks
    cast4_f32_bf16<<<dim3((n4w + 255) / 256, 1, 4), 256, 0, stream>>>(
        Wq, Wk, Wv, Wo, Wq_bf, Wk_bf, Wv_bf, Wo_bf, n4w);
  }

  gemm_qkv<<<dim3(D_ / 128, (B_ * S_) / 128, 3), 256, 0, stream>>>(
      qi_bf, ki_bf, vi_bf, Wq_bf, Wk_bf, Wv_bf, Qf, Kf, Vf);

  compute_z<<<dim3(S_ / 64, S_ / 128, B_), 256, 0, stream>>>(Qf, Kf, Zl);
  attn_pv<<<dim3(H_, S_ / 64, B_), 256, 0, stream>>>(Qf, Kf, Vf, Zl, Xb);

  gemm_out<<<dim3(8, 64), 256, 0, stream>>>(Xb, Wo_bf, (float*)d_out);
}

// Round 10
// 300.980 us; speedup vs baseline: 1.1273x; 1.0098x over previous
//
#include <hip/hip_runtime.h>
#include <stdint.h>

// Problem constants (reference: B=2, S=2048, D=1024, H=16, DK=64)
#define B_  2
#define S_  2048
#define D_  1024
#define H_  16
#define DK_ 64
#define PERHEAD (S_ * DK_)  // 131072 elems per (b,h)

// exp(x*0.125) = exp2(x * 0.125*log2(e))
#define EXP2SCALE 0.18033688011112042f

typedef __attribute__((ext_vector_type(8))) short short8;   // 8 bf16 = 4 VGPRs (MFMA A/B frag)
typedef __attribute__((ext_vector_type(4))) float floatx4;  // MFMA C/D frag

#define MFMA16(a, b, c) __builtin_amdgcn_mfma_f32_16x16x32_bf16((a), (b), (c), 0, 0, 0)

// async global->LDS, 16B per lane (used only in the projection GEMMs)
__device__ __forceinline__ void gload_lds16(const void* g, void* lds) {
  __builtin_amdgcn_global_load_lds(
      (__attribute__((address_space(1))) void*)(void*)g,
      (__attribute__((address_space(3))) void*)lds, 16, 0, 0);
}

__device__ __forceinline__ unsigned short f2bf(float f) {
  union { float f; unsigned int u; } v;
  v.f = f;
  unsigned int r = v.u + 0x7fffu + ((v.u >> 16) & 1u);
  return (unsigned short)(r >> 16);
}

// pack two positive f32 into two bf16 (round-half-up: +0x8000 then take hi16 via v_perm)
__device__ __forceinline__ unsigned int pack_bf16_rhu(float e0, float e1) {
  unsigned int u0 = __float_as_uint(e0) + 0x8000u;
  unsigned int u1 = __float_as_uint(e1) + 0x8000u;
  return __builtin_amdgcn_perm(u1, u0, 0x07060302);  // {u1.hi16, u0.hi16}
}

// ---------------- single batched cast fp32 -> bf16 (7 tensors, one launch) ----------
// z 0..2: token inputs (n4 = NT/4 quads); z 3..6: weights (n4w = NW/4 quads).
__global__ void cast_all(const float* __restrict__ a0, const float* __restrict__ a1,
                         const float* __restrict__ a2, const float* __restrict__ a3,
                         const float* __restrict__ a4, const float* __restrict__ a5,
                         const float* __restrict__ a6,
                         unsigned short* __restrict__ o0, unsigned short* __restrict__ o1,
                         unsigned short* __restrict__ o2, unsigned short* __restrict__ o3,
                         unsigned short* __restrict__ o4, unsigned short* __restrict__ o5,
                         unsigned short* __restrict__ o6,
                         int n4tok, int n4w) {
  const int z = blockIdx.z;
  const float* in = (z == 0) ? a0 : (z == 1) ? a1 : (z == 2) ? a2 : (z == 3) ? a3
                    : (z == 4) ? a4 : (z == 5) ? a5 : a6;
  unsigned short* out = (z == 0) ? o0 : (z == 1) ? o1 : (z == 2) ? o2 : (z == 3) ? o3
                        : (z == 4) ? o4 : (z == 5) ? o5 : o6;
  const int n4 = (z < 3) ? n4tok : n4w;
  int i = blockIdx.x * 256 + threadIdx.x;
  if (i < n4) {
    float4 f = ((const float4*)in)[i];
    uint2 p;
    p.x = (unsigned int)f2bf(f.x) | ((unsigned int)f2bf(f.y) << 16);
    p.y = (unsigned int)f2bf(f.z) | ((unsigned int)f2bf(f.w) << 16);
    ((uint2*)out)[i] = p;
  }
}

// Fragment-ordered layouts (16x16x32 MFMA operand fragments; one frag = 16 rows x
// 32 k x bf16 = 512 elems = 64 lane-ordered 16B chunks; chunk L = row(L&15),
// k = (L>>4)*8..+7). Reader: ds/global _b128 at base + lane*16 -> conflict-free.
//
// Qf/Kf per (b,h): frag(sblk = s>>4, ks = dk>>5):  idx = sblk*2 + ks
// Vf    per (b,h): frag(kblk = key>>5, db = dk>>4): idx = kblk*4 + db  (rows = dk)

// ---------------- shared GEMM core: 128x128 tile, BK=32, 4 waves each 64x64 ----------
__device__ __forceinline__ void gemm_core(const unsigned short* __restrict__ A,
                                          const unsigned short* __restrict__ Bw,
                                          unsigned short* lA, unsigned short* lB,
                                          int m0, int n0, int tid, int lane, int wave,
                                          floatx4 acc[4][4]) {
  const int wm = (wave >> 1) * 64;
  const int wn = (wave & 1) * 64;
  for (int k0 = 0; k0 < D_; k0 += 32) {
#pragma unroll
    for (int l = 0; l < 2; ++l) {
      int c = l * 256 + tid;
      int row = c >> 2, cb = (c & 3) * 16;
      const char* ga = (const char*)A + ((size_t)(m0 + row) * D_ + k0) * 2 + cb;
      gload_lds16(ga, (char*)lA + (size_t)(l * 256 + wave * 64) * 16);
      const char* gb = (const char*)Bw + ((size_t)(n0 + row) * D_ + k0) * 2 + cb;
      gload_lds16(gb, (char*)lB + (size_t)(l * 256 + wave * 64) * 16);
    }
    __syncthreads();
    short8 af[4], bf_[4];
#pragma unroll
    for (int mt = 0; mt < 4; ++mt)
      af[mt] = *(const short8*)&lA[(wm + mt * 16 + (lane & 15)) * 32 + (lane >> 4) * 8];
#pragma unroll
    for (int nt = 0; nt < 4; ++nt)
      bf_[nt] = *(const short8*)&lB[(wn + nt * 16 + (lane & 15)) * 32 + (lane >> 4) * 8];
#pragma unroll
    for (int mt = 0; mt < 4; ++mt)
#pragma unroll
      for (int nt = 0; nt < 4; ++nt)
        acc[mt][nt] = MFMA16(af[mt], bf_[nt], acc[mt][nt]);
    __syncthreads();
  }
}

// ---------------- fused QKV projection: z selects (A, W, Out, epilogue) ----------------
// XCD swizzle (r8): XCD owns m-tiles [xcd*4, xcd*4+4) for all n, z slowest ->
// hot set ~3 MB (A panel 1 MB + B 2 MB), L2-resident. 768 = 8 xcd x 8 n x 4 m x 3 z.
// (256,3) since r9: grid = exactly 3 blocks/CU.
__launch_bounds__(256, 3)
__global__ void gemm_qkv(const unsigned short* __restrict__ qi, const unsigned short* __restrict__ ki,
                         const unsigned short* __restrict__ vi,
                         const unsigned short* __restrict__ Wq, const unsigned short* __restrict__ Wk,
                         const unsigned short* __restrict__ Wv,
                         unsigned short* __restrict__ Qf, unsigned short* __restrict__ Kf,
                         unsigned short* __restrict__ Vf) {
  __shared__ unsigned short lA[128 * 32];
  __shared__ unsigned short lB[128 * 32];
  const int f = blockIdx.x + 8 * blockIdx.y + 256 * blockIdx.z;
  const int xcd = f & 7, j = f >> 3;              // j in [0,96)
  const int n0 = (j & 7) * 128;                   // n-tile
  const int m0 = (xcd * 4 + ((j >> 3) & 3)) * 128;  // m-tile: XCD-chunked
  const int z  = j >> 5;                          // 0..2, slowest
  const unsigned short* A  = (z == 0) ? qi : (z == 1) ? ki : vi;
  const unsigned short* Bw = (z == 0) ? Wq : (z == 1) ? Wk : Wv;
  unsigned short* O        = (z == 0) ? Qf : (z == 1) ? Kf : Vf;
  const int tid = threadIdx.x, lane = tid & 63, wave = tid >> 6;
  const int wm = (wave >> 1) * 64, wn = (wave & 1) * 64;

  floatx4 acc[4][4] = {};
  gemm_core(A, Bw, lA, lB, m0, n0, tid, lane, wave, acc);

  if (z < 2) {  // Qf/Kf fragment layout
#pragma unroll
    for (int mt = 0; mt < 4; ++mt)
#pragma unroll
      for (int nt = 0; nt < 4; ++nt)
#pragma unroll
        for (int r = 0; r < 4; ++r) {
          int row = m0 + wm + mt * 16 + (lane >> 4) * 4 + r;  // token
          int col = n0 + wn + nt * 16 + (lane & 15);          // e
          int b = row >> 11, s = row & (S_ - 1);
          int h = col >> 6,  dk = col & 63;
          size_t base = (size_t)(b * H_ + h) * PERHEAD;
          int frag = (s >> 4) * 2 + (dk >> 5);
          int lp = (s & 15) | (((dk >> 3) & 3) << 4);
          O[base + (size_t)frag * 512 + lp * 8 + (dk & 7)] = f2bf(acc[mt][nt][r]);
        }
  } else {  // Vf fragment layout (rows = dk, k = key)
#pragma unroll
    for (int mt = 0; mt < 4; ++mt)
#pragma unroll
      for (int nt = 0; nt < 4; ++nt) {
        int row0 = m0 + wm + mt * 16 + (lane >> 4) * 4;  // 4 consecutive keys
        int col  = n0 + wn + nt * 16 + (lane & 15);
        int b = row0 >> 11, key0 = row0 & (S_ - 1);
        int h = col >> 6,   dk = col & 63;
        size_t base = (size_t)(b * H_ + h) * PERHEAD;
        int frag = (key0 >> 5) * 4 + (dk >> 4);
        int lp = (dk & 15) | (((key0 >> 3) & 3) << 4);
        unsigned long long pk =
            (unsigned long long)f2bf(acc[mt][nt][0]) |
            ((unsigned long long)f2bf(acc[mt][nt][1]) << 16) |
            ((unsigned long long)f2bf(acc[mt][nt][2]) << 32) |
            ((unsigned long long)f2bf(acc[mt][nt][3]) << 48);
        *(unsigned long long*)&O[base + (size_t)frag * 512 + lp * 8 + (key0 & 7)] = pk;
      }
  }
}

// ---------------- output projection: fp32 row-major ----------------
// r9: 64x128 tile, 512 blocks = 2/CU; XCD owns m-tiles [xcd*8, xcd*8+8).
__launch_bounds__(256, 2)
__global__ void gemm_out(const unsigned short* __restrict__ A, const unsigned short* __restrict__ Bw,
                         float* __restrict__ O) {
  __shared__ unsigned short lA[64 * 32];
  __shared__ unsigned short lB[128 * 32];
  const int f = blockIdx.x + 8 * blockIdx.y;      // grid (8, 64) = 512 blocks
  const int xcd = f & 7, j = f >> 3;              // j in [0,64)
  const int n0 = (j & 7) * 128;
  const int m0 = (xcd * 8 + (j >> 3)) * 64;       // m-tile (64 rows): XCD-chunked
  const int tid = threadIdx.x, lane = tid & 63, wave = tid >> 6;
  const int wm = (wave >> 1) * 32, wn = (wave & 1) * 64;
  floatx4 acc[2][4] = {};
  for (int k0 = 0; k0 < D_; k0 += 32) {
    {  // A: 64x32 tile = 256 x 16B chunks, one per thread
      int c = tid;
      int row = c >> 2, cb = (c & 3) * 16;
      const char* ga = (const char*)A + ((size_t)(m0 + row) * D_ + k0) * 2 + cb;
      gload_lds16(ga, (char*)lA + (size_t)(wave * 64) * 16);
    }
#pragma unroll
    for (int l = 0; l < 2; ++l) {  // B: 128x32 tile = 512 chunks, two per thread
      int c = l * 256 + tid;
      int row = c >> 2, cb = (c & 3) * 16;
      const char* gb = (const char*)Bw + ((size_t)(n0 + row) * D_ + k0) * 2 + cb;
      gload_lds16(gb, (char*)lB + (size_t)(l * 256 + wave * 64) * 16);
    }
    __syncthreads();
    short8 af[2], bf_[4];
#pragma unroll
    for (int mt = 0; mt < 2; ++mt)
      af[mt] = *(const short8*)&lA[(wm + mt * 16 + (lane & 15)) * 32 + (lane >> 4) * 8];
#pragma unroll
    for (int nt = 0; nt < 4; ++nt)
      bf_[nt] = *(const short8*)&lB[(wn + nt * 16 + (lane & 15)) * 32 + (lane >> 4) * 8];
#pragma unroll
    for (int mt = 0; mt < 2; ++mt)
#pragma unroll
      for (int nt = 0; nt < 4; ++nt)
        acc[mt][nt] = MFMA16(af[mt], bf_[nt], acc[mt][nt]);
    __syncthreads();
  }
#pragma unroll
  for (int mt = 0; mt < 2; ++mt)
#pragma unroll
    for (int nt = 0; nt < 4; ++nt)
#pragma unroll
      for (int r = 0; r < 4; ++r) {
        int row = m0 + wm + mt * 16 + (lane >> 4) * 4 + r;
        int col = n0 + wn + nt * 16 + (lane & 15);
        O[(size_t)row * D_ + col] = acc[mt][nt][r];
      }
}

// ---------------- Pass 1: Zl[b,q,k] = fp16( log2( sum_h exp2(s*C) ) ) ----------------
// r8: k-tile 64, 1024 blocks = 4 blocks/CU, (256,4). Kept (part of 303.9 best).
__launch_bounds__(256, 4)
__global__ void compute_z(const unsigned short* __restrict__ Qf,
                          const unsigned short* __restrict__ Kf,
                          unsigned short* __restrict__ Zl) {
  const int tid = threadIdx.x, lane = tid & 63, wave = tid >> 6;
  const int k0 = blockIdx.x * 64, q0 = blockIdx.y * 128, b = blockIdx.z;

  floatx4 zacc[2][4] = {};
  const short8* qbase = (const short8*)Qf + (size_t)b * H_ * (PERHEAD / 8)
                        + ((q0 >> 4) + wave * 2) * 128 + lane;
  const short8* kbase = (const short8*)Kf + (size_t)b * H_ * (PERHEAD / 8)
                        + (k0 >> 4) * 128 + lane;

#pragma unroll 1
  for (int h = 0; h < H_; ++h) {
    short8 qf0 = qbase[0], qf1 = qbase[64];    // sq=0, ks=0/1
    short8 qf2 = qbase[128], qf3 = qbase[192]; // sq=1, ks=0/1
    short8 kst[4][2];
#pragma unroll
    for (int kb = 0; kb < 4; ++kb) {
      kst[kb][0] = kbase[kb * 128];
      kst[kb][1] = kbase[kb * 128 + 64];
    }
#pragma unroll
    for (int kb = 0; kb < 4; ++kb) {
      floatx4 s0 = {}, s1 = {};
      s0 = MFMA16(qf0, kst[kb][0], s0);
      s0 = MFMA16(qf1, kst[kb][1], s0);
      s1 = MFMA16(qf2, kst[kb][0], s1);
      s1 = MFMA16(qf3, kst[kb][1], s1);
#pragma unroll
      for (int r = 0; r < 4; ++r) {
        zacc[0][kb][r] += exp2f(s0[r] * EXP2SCALE);
        zacc[1][kb][r] += exp2f(s1[r] * EXP2SCALE);
      }
    }
    qbase += PERHEAD / 8;
    kbase += PERHEAD / 8;
  }

#pragma unroll
  for (int sq = 0; sq < 2; ++sq)
#pragma unroll
    for (int kb = 0; kb < 4; ++kb)
#pragma unroll
      for (int r = 0; r < 4; ++r) {
        int q = q0 + wave * 32 + sq * 16 + (lane >> 4) * 4 + r;
        int k = k0 + kb * 16 + (lane & 15);
        union { _Float16 h; unsigned short u; } cv;
        cv.h = (_Float16)log2f(zacc[sq][kb][r]);
        Zl[((size_t)b * S_ + q) * S_ + k] = cv.u;
      }
}

// ---------------- Pass 2: x^T = exp2(s*C - Lz) @ V ----------------
// Round-10: EXACT r0 body, __launch_bounds__ (256,3) -> (256,4).
// Issue audit: per-block iter wall ~= 4800 cy; each wave's serial chain
// (K load ~200cy un-prefetched -> QK -> exp -> LDS -> barrier -> PV) ~= 1600 cy;
// wall = chain / blocks-per-SIMD. Grid gives 4 blocks/CU (1024/256) but the old
// bound capped residency at 3. VGPR 64 / LDS 16 KB both fit 4+ blocks -> no
// spill possible (cap 128). r4's occupancy try failed because it SHRANK the tile
// (2x per-work K/V traffic + forced spill); this keeps the tile.
// Head partition preserved (f mod 8 = h mod 8 -> 2 MB K/V per XCD, L2-resident).
__launch_bounds__(256, 4)
__global__ void attn_pv(const unsigned short* __restrict__ Qf,
                        const unsigned short* __restrict__ Kf,
                        const unsigned short* __restrict__ Vf,
                        const unsigned short* __restrict__ Zl,
                        unsigned short* __restrict__ X) {
  __shared__ unsigned short lP[2 * 4096];  // 2 bufs x (64q x 64k) fragment-ordered
  const int tid = threadIdx.x, lane = tid & 63, wave = tid >> 6;
  const int h = blockIdx.x, b = blockIdx.z;
  const int q0 = blockIdx.y * 64;

  const size_t headf = (size_t)(b * H_ + h) * (PERHEAD / 8);  // short8 units
  short8 qf[4][2];
#pragma unroll
  for (int qb = 0; qb < 4; ++qb) {
    const short8* qp = (const short8*)Qf + headf + ((q0 >> 4) + qb) * 128 + lane;
    qf[qb][0] = qp[0];
    qf[qb][1] = qp[64];
  }
  const short8* kp = (const short8*)Kf + headf + wave * 128 + lane;  // += 512/iter
  const short8* vp = (const short8*)Vf + headf + wave * 64 + lane;   // += 512/iter
  const unsigned short* zp = Zl + ((size_t)b * S_ + q0 + (lane & 15)) * S_
                             + wave * 16 + ((lane >> 4) << 2);

  // P write offset (ushort units, within one 4096 tile region): fragment-ordered
  const int pw_off = ((wave >> 1) << 9)
                   + (((lane & 15) | (((wave & 1) << 1 | ((lane >> 4) >> 1)) << 4)) << 3)
                   + (((lane >> 4) & 1) << 2);

  floatx4 xacc[4] = {};  // x^T[dk = wave*16 + row][q = qb*16 + col]

  // prologue: load iteration 0's operands
  short8 ck0 = kp[0], ck1 = kp[64];
  short8 cv0 = vp[0], cv1 = vp[256];
  uint2 cz0 = *(const uint2*)(zp);
  uint2 cz1 = *(const uint2*)(zp + (size_t)16 * S_);
  uint2 cz2 = *(const uint2*)(zp + (size_t)32 * S_);
  uint2 cz3 = *(const uint2*)(zp + (size_t)48 * S_);
  kp += 512; vp += 512; zp += 64;

#pragma unroll 2
  for (int kt = 0; kt < S_ / 64; ++kt) {
    const int buf = (kt & 1) << 12;
    // prefetch next iteration (named registers; guarded on last iter)
    short8 nk0, nk1, nv0, nv1;
    uint2 nz0, nz1, nz2, nz3;
    if (kt != S_ / 64 - 1) {
      nk0 = kp[0];  nk1 = kp[64];
      nv0 = vp[0];  nv1 = vp[256];
      nz0 = *(const uint2*)(zp);
      nz1 = *(const uint2*)(zp + (size_t)16 * S_);
      nz2 = *(const uint2*)(zp + (size_t)32 * S_);
      nz3 = *(const uint2*)(zp + (size_t)48 * S_);
      kp += 512; vp += 512; zp += 64;
    }

    // S^T tiles: m = 16 keys (wave's), n = 64 q
    floatx4 sacc[4] = {};
#pragma unroll
    for (int qb = 0; qb < 4; ++qb) {
      sacc[qb] = MFMA16(ck0, qf[qb][0], sacc[qb]);
      sacc[qb] = MFMA16(ck1, qf[qb][1], sacc[qb]);
    }
    // P = exp2(s*C - Lz) -> bf16, fragment-ordered in LDS
#pragma unroll
    for (int qb = 0; qb < 4; ++qb) {
      uint2 zz = (qb == 0) ? cz0 : (qb == 1) ? cz1 : (qb == 2) ? cz2 : cz3;
      union { uint2 v; _Float16 hv[4]; } za; za.v = zz;
      float e0 = exp2f(fmaf(sacc[qb][0], EXP2SCALE, -(float)za.hv[0]));
      float e1 = exp2f(fmaf(sacc[qb][1], EXP2SCALE, -(float)za.hv[1]));
      float e2 = exp2f(fmaf(sacc[qb][2], EXP2SCALE, -(float)za.hv[2]));
      float e3 = exp2f(fmaf(sacc[qb][3], EXP2SCALE, -(float)za.hv[3]));
      uint2 p;
      p.x = pack_bf16_rhu(e0, e1);
      p.y = pack_bf16_rhu(e2, e3);
      *(uint2*)&lP[buf + (qb << 10) + pw_off] = p;
    }
    __syncthreads();

    // x^T += V_frag @ P  (conflict-free lane*16 reads)
#pragma unroll
    for (int qb = 0; qb < 4; ++qb) {
      short8 p0 = *(const short8*)&lP[buf + (qb << 10) + (lane << 3)];
      short8 p1 = *(const short8*)&lP[buf + (qb << 10) + 512 + (lane << 3)];
      xacc[qb] = MFMA16(cv0, p0, xacc[qb]);
      xacc[qb] = MFMA16(cv1, p1, xacc[qb]);
    }

    // rotate prefetched -> current (renames under unroll)
    ck0 = nk0; ck1 = nk1; cv0 = nv0; cv1 = nv1;
    cz0 = nz0; cz1 = nz1; cz2 = nz2; cz3 = nz3;
  }

  // epilogue: transpose x^T -> x via padded LDS, then coalesced 16B stores
  __syncthreads();
  unsigned short* lX = lP;  // 64 rows(q) x 72 (dk padded)
#pragma unroll
  for (int qb = 0; qb < 4; ++qb)
#pragma unroll
    for (int r = 0; r < 4; ++r) {
      int q  = qb * 16 + (lane & 15);
      int dk = wave * 16 + (lane >> 4) * 4 + r;
      lX[q * 72 + dk] = f2bf(xacc[qb][r]);
    }
  __syncthreads();
  {
    int q = tid >> 2, cg = (tid & 3) * 16;
    short8 v0 = *(const short8*)&lX[q * 72 + cg];
    short8 v1 = *(const short8*)&lX[q * 72 + cg + 8];
    unsigned short* o = X + (size_t)(b * S_ + q0 + q) * D_ + h * DK_ + cg;
    *(short8*)&o[0] = v0;
    *(short8*)&o[8] = v1;
  }
}

// ---------------- launch ----------------
extern "C" void kernel_launch(void* const* d_in, const int* in_sizes, int n_in,
                              void* d_out, int out_size, void* d_ws, size_t ws_size,
                              hipStream_t stream) {
  const float* qi = (const float*)d_in[0];
  const float* ki = (const float*)d_in[1];
  const float* vi = (const float*)d_in[2];
  // d_in[3] = mask: reference discards masked_fill result -> unused
  const float* Wq = (const float*)d_in[4];
  const float* Wk = (const float*)d_in[5];
  const float* Wv = (const float*)d_in[6];
  const float* Wo = (const float*)d_in[7];

  const size_t NT = (size_t)B_ * S_ * D_;  // 4,194,304
  const size_t NW = (size_t)D_ * D_;       // 1,048,576

  unsigned short* w = (unsigned short*)d_ws;
  unsigned short* qi_bf = w; w += NT;
  unsigned short* ki_bf = w; w += NT;
  unsigned short* vi_bf = w; w += NT;
  unsigned short* Wq_bf = w; w += NW;
  unsigned short* Wk_bf = w; w += NW;
  unsigned short* Wv_bf = w; w += NW;
  unsigned short* Wo_bf = w; w += NW;
  unsigned short* Qf = w; w += NT;  // fragment-ordered per (b,h)
  unsigned short* Kf = w; w += NT;
  unsigned short* Vf = w; w += NT;
  unsigned short* Xb = w; w += NT;  // [b,s,e] row-major bf16
  unsigned short* Zl = w;           // [b,q,k] fp16 log2(Z), 16 MiB

  {
    int n4tok = (int)(NT / 4);  // 1048576 quads
    int n4w   = (int)(NW / 4);  // 262144 quads
    cast_all<<<dim3((n4tok + 255) / 256, 1, 7), 256, 0, stream>>>(
        qi, ki, vi, Wq, Wk, Wv, Wo,
        qi_bf, ki_bf, vi_bf, Wq_bf, Wk_bf, Wv_bf, Wo_bf, n4tok, n4w);
  }

  gemm_qkv<<<dim3(D_ / 128, (B_ * S_) / 128, 3), 256, 0, stream>>>(
      qi_bf, ki_bf, vi_bf, Wq_bf, Wk_bf, Wv_bf, Qf, Kf, Vf);

  compute_z<<<dim3(S_ / 64, S_ / 128, B_), 256, 0, stream>>>(Qf, Kf, Zl);
  attn_pv<<<dim3(H_, S_ / 64, B_), 256, 0, stream>>>(Qf, Kf, Vf, Zl, Xb);

  gemm_out<<<dim3(8, 64), 256, 0, stream>>>(Xb, Wo_bf, (float*)d_out);
}